// Round 7
// baseline (683.703 us; speedup 1.0000x reference)
//
#include <hip/hip_runtime.h>

typedef unsigned short u16;
typedef __attribute__((ext_vector_type(8))) short bf16x8;
typedef __attribute__((ext_vector_type(4))) float f32x4;

__device__ __forceinline__ float bf2f(u16 u){
  union { unsigned int i; float f; } v; v.i = ((unsigned int)u) << 16; return v.f;
}
__device__ __forceinline__ u16 f2bf(float f){
  union { float f; unsigned int i; } v; v.f = f;
  unsigned int lsb = (v.i >> 16) & 1u;
  v.i += 0x7fffu + lsb;
  return (u16)(v.i >> 16);
}
__device__ __forceinline__ void fma2(float& a0, float& a1, unsigned p, float s){
  union { unsigned u; float f; } lo, hi;
  lo.u = p << 16; hi.u = p & 0xffff0000u;
  a0 += s * lo.f; a1 += s * hi.f;
}

// ---------------- dtype sniffer ----------------
__global__ void k_sniff(const u16* __restrict__ p, int* __restrict__ flag){
  __shared__ int s[256];
  int tid = threadIdx.x;
  u16 v = p[2 * tid];
  int e = (v >> 7) & 0xFF;
  s[tid] = (e >= 100 && e <= 135) ? 1 : 0;
  __syncthreads();
  for (int off = 128; off; off >>= 1){
    if (tid < off) s[tid] += s[tid + off];
    __syncthreads();
  }
  if (tid == 0) *flag = (s[0] < 180) ? 1 : 0;
}
__global__ void k_canon(const void* __restrict__ src, u16* __restrict__ dst,
                        int n, const int* __restrict__ flag){
  int i = blockIdx.x * 256 + threadIdx.x;
  if (i < n){
    if (*flag) dst[i] = f2bf(((const float*)src)[i]);
    else       dst[i] = ((const u16*)src)[i];
  }
}
struct CanonEnt { const void* s; u16* d; int n; };
struct Canon10 { CanonEnt e[10]; };
__global__ void k_canon10(Canon10 c, const int* __restrict__ flag){
  CanonEnt en = c.e[blockIdx.y];
  int i = blockIdx.x * 256 + threadIdx.x;
  if (i < en.n){
    if (*flag) en.d[i] = f2bf(((const float*)en.s)[i]);
    else       en.d[i] = ((const u16*)en.s)[i];
  }
}
struct CanonWEnt { const void* s; u16* wt; int K; };
struct CanonW4 { CanonWEnt e[4]; };
__global__ void k_canonw(CanonW4 c, const int* __restrict__ flag){
  CanonWEnt en = c.e[blockIdx.y];
  int i = blockIdx.x * 256 + threadIdx.x;
  if (i < 256 * en.K){
    int k = i >> 8, cc = i & 255;
    u16 b;
    if (*flag) b = f2bf(((const float*)en.s)[i]);
    else       b = ((const u16*)en.s)[i];
    en.wt[(size_t)cc * en.K + k] = b;
  }
}

// ---------------- CSR build ----------------
__global__ void k_hist(const int* __restrict__ dst, int* __restrict__ cnt, int E){
  int i = blockIdx.x * 256 + threadIdx.x;
  if (i < E) atomicAdd(&cnt[dst[i]], 1);
}
__global__ void k_scan1(const int* __restrict__ cnt, int* __restrict__ rowptr,
                        int* __restrict__ bsums, int N){
  __shared__ int s[256];
  int i = blockIdx.x * 256 + threadIdx.x;
  int v = (i < N) ? cnt[i] : 0;
  s[threadIdx.x] = v; __syncthreads();
  for (int off = 1; off < 256; off <<= 1){
    int x = 0;
    if (threadIdx.x >= off) x = s[threadIdx.x - off];
    __syncthreads();
    s[threadIdx.x] += x;
    __syncthreads();
  }
  if (i < N) rowptr[i + 1] = s[threadIdx.x];
  if (threadIdx.x == 255) bsums[blockIdx.x] = s[255];
}
__global__ void k_scan2(int* __restrict__ bsums, int nb){
  __shared__ int s[256];
  int t = threadIdx.x;
  int v = (t < nb) ? bsums[t] : 0;
  s[t] = v; __syncthreads();
  for (int off = 1; off < 256; off <<= 1){
    int x = 0;
    if (t >= off) x = s[t - off];
    __syncthreads();
    s[t] += x;
    __syncthreads();
  }
  if (t < nb) bsums[t] = s[t] - v;                // exclusive
}
__global__ void k_scan3(int* __restrict__ rowptr, const int* __restrict__ bsums,
                        int* __restrict__ cursor, int N){
  int i = blockIdx.x * 256 + threadIdx.x;
  if (i < N){
    int v = rowptr[i + 1] + bsums[blockIdx.x];
    rowptr[i + 1] = v;
    if (i + 1 < N) cursor[i + 1] = v;
    if (i == 0){ rowptr[0] = 0; cursor[0] = 0; }
  }
}
__global__ void k_scatter(const int* __restrict__ src, const int* __restrict__ dst,
                          int* __restrict__ cursor, int* __restrict__ csr_src,
                          int* __restrict__ csr_dst, int* __restrict__ csr_eid, int E){
  int i = blockIdx.x * 256 + threadIdx.x;
  if (i < E){
    int p = atomicAdd(&cursor[dst[i]], 1);
    csr_src[p] = src[i];
    csr_dst[p] = dst[i];
    csr_eid[p] = i;
  }
}

// ---------------- MFMA node GEMM v2: 32 rows/wave, 128 rows/block -------------
__global__ __launch_bounds__(256) void mfma_gemm2(
    const u16* __restrict__ X, const u16* __restrict__ WT,
    u16* __restrict__ OUT, int N, int K)
{
  const int wave = threadIdx.x >> 6;
  const int lane = threadIdx.x & 63;
  const int m = lane & 15;
  const int q = lane >> 4;
  const int row0 = blockIdx.x * 128 + wave * 32;
  f32x4 acc[2][16];
  #pragma unroll
  for (int g = 0; g < 2; ++g)
    #pragma unroll
    for (int t = 0; t < 16; ++t) acc[g][t] = (f32x4){0.f, 0.f, 0.f, 0.f};
  const int rA = row0 + m, rB = row0 + 16 + m;
  const bool vA = rA < N, vB = rB < N;
  const u16* apA = X + (size_t)rA * K + q * 8;
  const u16* apB = X + (size_t)rB * K + q * 8;
  for (int k0 = 0; k0 < K; k0 += 32){
    bf16x8 aA = {}, aB = {};
    if (vA) aA = *(const bf16x8*)(apA + k0);
    if (vB) aB = *(const bf16x8*)(apB + k0);
    #pragma unroll
    for (int t = 0; t < 16; ++t){
      const u16* bptr = WT + (size_t)(t * 16 + m) * K + k0 + q * 8;
      bf16x8 b = *(const bf16x8*)bptr;
      acc[0][t] = __builtin_amdgcn_mfma_f32_16x16x32_bf16(aA, b, acc[0][t], 0, 0, 0);
      acc[1][t] = __builtin_amdgcn_mfma_f32_16x16x32_bf16(aB, b, acc[1][t], 0, 0, 0);
    }
  }
  #pragma unroll
  for (int g = 0; g < 2; ++g)
    #pragma unroll
    for (int t = 0; t < 16; ++t){
      int col = t * 16 + m;
      #pragma unroll
      for (int r = 0; r < 4; ++r){
        int rr = row0 + g * 16 + q * 4 + r;
        if (rr < N) OUT[(size_t)rr * 256 + col] = f2bf(acc[g][t][r]);
      }
    }
}

// ---------------- MFMA node GEMM v2 + fused attention logits ------------------
__global__ __launch_bounds__(256) void mfma_gemm_attn2(
    const u16* __restrict__ X, const u16* __restrict__ WT,
    u16* __restrict__ OUT, const u16* __restrict__ al, const u16* __restrict__ ar,
    float* __restrict__ el4, float* __restrict__ er4, int N, int K)
{
  const int wave = threadIdx.x >> 6;
  const int lane = threadIdx.x & 63;
  const int m = lane & 15;
  const int q = lane >> 4;
  const int row0 = blockIdx.x * 128 + wave * 32;
  f32x4 acc[2][16];
  #pragma unroll
  for (int g = 0; g < 2; ++g)
    #pragma unroll
    for (int t = 0; t < 16; ++t) acc[g][t] = (f32x4){0.f, 0.f, 0.f, 0.f};
  const int rA = row0 + m, rB = row0 + 16 + m;
  const bool vA = rA < N, vB = rB < N;
  const u16* apA = X + (size_t)rA * K + q * 8;
  const u16* apB = X + (size_t)rB * K + q * 8;
  for (int k0 = 0; k0 < K; k0 += 32){
    bf16x8 aA = {}, aB = {};
    if (vA) aA = *(const bf16x8*)(apA + k0);
    if (vB) aB = *(const bf16x8*)(apB + k0);
    #pragma unroll
    for (int t = 0; t < 16; ++t){
      const u16* bptr = WT + (size_t)(t * 16 + m) * K + k0 + q * 8;
      bf16x8 b = *(const bf16x8*)bptr;
      acc[0][t] = __builtin_amdgcn_mfma_f32_16x16x32_bf16(aA, b, acc[0][t], 0, 0, 0);
      acc[1][t] = __builtin_amdgcn_mfma_f32_16x16x32_bf16(aB, b, acc[1][t], 0, 0, 0);
    }
  }
  // attn vectors loaded after the K-loop (keeps loop-live VGPRs low)
  float alv[16], arv[16];
  #pragma unroll
  for (int t = 0; t < 16; ++t){
    alv[t] = bf2f(al[t * 16 + m]);
    arv[t] = bf2f(ar[t * 16 + m]);
  }
  #pragma unroll
  for (int g = 0; g < 2; ++g)
    #pragma unroll
    for (int r = 0; r < 4; ++r){
      float pe[4] = {0.f, 0.f, 0.f, 0.f}, pr[4] = {0.f, 0.f, 0.f, 0.f};
      #pragma unroll
      for (int t = 0; t < 16; ++t){
        pe[t >> 2] += acc[g][t][r] * alv[t];
        pr[t >> 2] += acc[g][t][r] * arv[t];
      }
      #pragma unroll
      for (int mk = 1; mk < 16; mk <<= 1){
        #pragma unroll
        for (int hh = 0; hh < 4; ++hh){
          pe[hh] += __shfl_xor(pe[hh], mk);
          pr[hh] += __shfl_xor(pr[hh], mk);
        }
      }
      int rr = row0 + g * 16 + q * 4 + r;
      if (m == 0 && rr < N){
        *(f32x4*)(el4 + (size_t)rr * 4) = (f32x4){pe[0], pe[1], pe[2], pe[3]};
        *(f32x4*)(er4 + (size_t)rr * 4) = (f32x4){pr[0], pr[1], pr[2], pr[3]};
      }
    }
  #pragma unroll
  for (int g = 0; g < 2; ++g)
    #pragma unroll
    for (int t = 0; t < 16; ++t){
      int col = t * 16 + m;
      #pragma unroll
      for (int r = 0; r < 4; ++r){
        int rr = row0 + g * 16 + q * 4 + r;
        if (rr < N) OUT[(size_t)rr * 256 + col] = f2bf(acc[g][t][r]);
      }
    }
}

// ---------------- layer-1 dual GEMM: FT = X*W1 (+attn), XA = X*Wr1 ------------
// 16 rows/wave, 64 rows/block; A-fragments shared between the two B matrices.
__global__ __launch_bounds__(256) void mfma_gemm_dual(
    const u16* __restrict__ X, const u16* __restrict__ WT, const u16* __restrict__ WTr,
    u16* __restrict__ FT, u16* __restrict__ XA,
    const u16* __restrict__ al, const u16* __restrict__ ar,
    float* __restrict__ el4, float* __restrict__ er4, int N, int K)
{
  const int wave = threadIdx.x >> 6;
  const int lane = threadIdx.x & 63;
  const int m = lane & 15;
  const int q = lane >> 4;
  const int row0 = blockIdx.x * 64 + wave * 16;
  f32x4 acc[16], accR[16];
  #pragma unroll
  for (int t = 0; t < 16; ++t){
    acc[t] = (f32x4){0.f, 0.f, 0.f, 0.f};
    accR[t] = (f32x4){0.f, 0.f, 0.f, 0.f};
  }
  const int arow = row0 + m;
  const bool rvalid = arow < N;
  const u16* aptr = X + (size_t)arow * K + q * 8;
  for (int k0 = 0; k0 < K; k0 += 32){
    bf16x8 a = {};
    if (rvalid) a = *(const bf16x8*)(aptr + k0);
    #pragma unroll
    for (int t = 0; t < 16; ++t){
      size_t off = (size_t)(t * 16 + m) * K + k0 + q * 8;
      bf16x8 b1 = *(const bf16x8*)(WT + off);
      bf16x8 b2 = *(const bf16x8*)(WTr + off);
      acc[t]  = __builtin_amdgcn_mfma_f32_16x16x32_bf16(a, b1, acc[t], 0, 0, 0);
      accR[t] = __builtin_amdgcn_mfma_f32_16x16x32_bf16(a, b2, accR[t], 0, 0, 0);
    }
  }
  float alv[16], arv[16];
  #pragma unroll
  for (int t = 0; t < 16; ++t){
    alv[t] = bf2f(al[t * 16 + m]);
    arv[t] = bf2f(ar[t * 16 + m]);
  }
  #pragma unroll
  for (int r = 0; r < 4; ++r){
    float pe[4] = {0.f, 0.f, 0.f, 0.f}, pr[4] = {0.f, 0.f, 0.f, 0.f};
    #pragma unroll
    for (int t = 0; t < 16; ++t){
      pe[t >> 2] += acc[t][r] * alv[t];
      pr[t >> 2] += acc[t][r] * arv[t];
    }
    #pragma unroll
    for (int mk = 1; mk < 16; mk <<= 1){
      #pragma unroll
      for (int hh = 0; hh < 4; ++hh){
        pe[hh] += __shfl_xor(pe[hh], mk);
        pr[hh] += __shfl_xor(pr[hh], mk);
      }
    }
    int rr = row0 + q * 4 + r;
    if (m == 0 && rr < N){
      *(f32x4*)(el4 + (size_t)rr * 4) = (f32x4){pe[0], pe[1], pe[2], pe[3]};
      *(f32x4*)(er4 + (size_t)rr * 4) = (f32x4){pr[0], pr[1], pr[2], pr[3]};
    }
  }
  #pragma unroll
  for (int t = 0; t < 16; ++t){
    int col = t * 16 + m;
    #pragma unroll
    for (int r = 0; r < 4; ++r){
      int rr = row0 + q * 4 + r;
      if (rr < N){
        FT[(size_t)rr * 256 + col] = f2bf(acc[t][r]);
        XA[(size_t)rr * 256 + col] = f2bf(accR[t][r]);
      }
    }
  }
}

// ---------------- aggregation v5: 1 wave = 1 dst, 16B/lane, 4 edges batched ---
__global__ __launch_bounds__(256) void aggregate5(
    const u16* __restrict__ ft, const float* __restrict__ el4, const float* __restrict__ er4,
    const int* __restrict__ rowptr, const int* __restrict__ csr_src,
    const u16* __restrict__ residb, u16* __restrict__ outb,
    u16* __restrict__ hf, int do_hf, int N)
{
  __shared__ float sal[4][64][4];
  __shared__ int   sof[4][64];
  const int w = threadIdx.x >> 6, lane = threadIdx.x & 63;
  const int d = blockIdx.x * 4 + w;
  if (d >= N) return;
  const int beg = rowptr[d], deg = rowptr[d + 1] - beg;
  const int H = lane >> 5;            // edge-parity half
  const int c = lane & 31;            // col group: cols c*8 .. c*8+7
  const int hg = c >> 3;              // head of those cols
  float acc[8] = {0.f, 0.f, 0.f, 0.f, 0.f, 0.f, 0.f, 0.f};

  if (deg > 0){
    const float4 erd = ((const float4*)er4)[d];
    const int dc = min(deg, 64);
    float m0 = -3.0e38f, m1 = -3.0e38f, m2 = -3.0e38f, m3 = -3.0e38f;
    float ec0 = 0.f, ec1 = 0.f, ec2 = 0.f, ec3 = 0.f; int sc = 0;
    for (int j = lane; j < deg; j += 64){
      int s = csr_src[beg + j];
      float4 ql = ((const float4*)el4)[s];
      float e0 = ql.x + erd.x; e0 = (e0 > 0.f) ? e0 : 0.2f * e0;
      float e1 = ql.y + erd.y; e1 = (e1 > 0.f) ? e1 : 0.2f * e1;
      float e2 = ql.z + erd.z; e2 = (e2 > 0.f) ? e2 : 0.2f * e2;
      float e3 = ql.w + erd.w; e3 = (e3 > 0.f) ? e3 : 0.2f * e3;
      if (j < 64){ ec0 = e0; ec1 = e1; ec2 = e2; ec3 = e3; sc = s; }
      m0 = fmaxf(m0, e0); m1 = fmaxf(m1, e1);
      m2 = fmaxf(m2, e2); m3 = fmaxf(m3, e3);
    }
    for (int mk = 1; mk < dc; mk <<= 1){
      m0 = fmaxf(m0, __shfl_xor(m0, mk)); m1 = fmaxf(m1, __shfl_xor(m1, mk));
      m2 = fmaxf(m2, __shfl_xor(m2, mk)); m3 = fmaxf(m3, __shfl_xor(m3, mk));
    }
    float x0 = 0.f, x1 = 0.f, x2 = 0.f, x3 = 0.f;
    float d0 = 0.f, d1 = 0.f, d2 = 0.f, d3 = 0.f;
    for (int j = lane; j < deg; j += 64){
      float e0, e1, e2, e3;
      if (j < 64){ e0 = ec0; e1 = ec1; e2 = ec2; e3 = ec3; }
      else {
        int s = csr_src[beg + j];
        float4 ql = ((const float4*)el4)[s];
        e0 = ql.x + erd.x; e0 = (e0 > 0.f) ? e0 : 0.2f * e0;
        e1 = ql.y + erd.y; e1 = (e1 > 0.f) ? e1 : 0.2f * e1;
        e2 = ql.z + erd.z; e2 = (e2 > 0.f) ? e2 : 0.2f * e2;
        e3 = ql.w + erd.w; e3 = (e3 > 0.f) ? e3 : 0.2f * e3;
      }
      float t0 = __expf(e0 - m0), t1 = __expf(e1 - m1);
      float t2 = __expf(e2 - m2), t3 = __expf(e3 - m3);
      if (j < 64){ x0 = t0; x1 = t1; x2 = t2; x3 = t3; }
      d0 += t0; d1 += t1; d2 += t2; d3 += t3;
    }
    for (int mk = 1; mk < dc; mk <<= 1){
      d0 += __shfl_xor(d0, mk); d1 += __shfl_xor(d1, mk);
      d2 += __shfl_xor(d2, mk); d3 += __shfl_xor(d3, mk);
    }
    const float i0 = 1.f / d0, i1 = 1.f / d1, i2 = 1.f / d2, i3 = 1.f / d3;

    for (int c0 = 0; c0 < deg; c0 += 64){
      int cs = min(64, deg - c0);
      if (lane < cs){
        float t0, t1, t2, t3; int s;
        if (c0 == 0){ t0 = x0; t1 = x1; t2 = x2; t3 = x3; s = sc; }
        else {
          s = csr_src[beg + c0 + lane];
          float4 ql = ((const float4*)el4)[s];
          float e0 = ql.x + erd.x; e0 = (e0 > 0.f) ? e0 : 0.2f * e0;
          float e1 = ql.y + erd.y; e1 = (e1 > 0.f) ? e1 : 0.2f * e1;
          float e2 = ql.z + erd.z; e2 = (e2 > 0.f) ? e2 : 0.2f * e2;
          float e3 = ql.w + erd.w; e3 = (e3 > 0.f) ? e3 : 0.2f * e3;
          t0 = __expf(e0 - m0); t1 = __expf(e1 - m1);
          t2 = __expf(e2 - m2); t3 = __expf(e3 - m3);
        }
        sal[w][lane][0] = t0 * i0; sal[w][lane][1] = t1 * i1;
        sal[w][lane][2] = t2 * i2; sal[w][lane][3] = t3 * i3;
        sof[w][lane] = s << 9;                      // s * 512 bytes
      }
      __builtin_amdgcn_wave_barrier();
      for (int j0 = 0; j0 < cs; j0 += 4){
        int jA = j0 + H, jB = j0 + 2 + H;
        bool bA = jA < cs, bB = jB < cs;
        float aA = 0.f, aB = 0.f;
        int offA = 0, offB = 0;
        if (bA){ aA = sal[w][jA][hg]; offA = sof[w][jA]; }
        if (bB){ aB = sal[w][jB][hg]; offB = sof[w][jB]; }
        uint4 vA = {}, vB = {};
        if (bA) vA = *(const uint4*)((const char*)ft + (size_t)(unsigned)offA + c * 16);
        if (bB) vB = *(const uint4*)((const char*)ft + (size_t)(unsigned)offB + c * 16);
        if (bA){
          fma2(acc[0], acc[1], vA.x, aA);
          fma2(acc[2], acc[3], vA.y, aA);
          fma2(acc[4], acc[5], vA.z, aA);
          fma2(acc[6], acc[7], vA.w, aA);
        }
        if (bB){
          fma2(acc[0], acc[1], vB.x, aB);
          fma2(acc[2], acc[3], vB.y, aB);
          fma2(acc[4], acc[5], vB.z, aB);
          fma2(acc[6], acc[7], vB.w, aB);
        }
      }
      __builtin_amdgcn_wave_barrier();
    }
  }
  // combine the two edge-parity halves
  #pragma unroll
  for (int i = 0; i < 8; ++i) acc[i] += __shfl_xor(acc[i], 32);
  uint4 rv = *(const uint4*)(residb + (size_t)d * 256 + c * 8);
  float rr[8];
  {
    union { unsigned u; float f; } t;
    t.u = rv.x << 16; rr[0] = t.f; t.u = rv.x & 0xffff0000u; rr[1] = t.f;
    t.u = rv.y << 16; rr[2] = t.f; t.u = rv.y & 0xffff0000u; rr[3] = t.f;
    t.u = rv.z << 16; rr[4] = t.f; t.u = rv.z & 0xffff0000u; rr[5] = t.f;
    t.u = rv.w << 16; rr[6] = t.f; t.u = rv.w & 0xffff0000u; rr[7] = t.f;
  }
  if (!do_hf){
    if (H == 0){
      uint4 ov;
      unsigned p[8];
      #pragma unroll
      for (int i = 0; i < 8; ++i) p[i] = f2bf(fmaxf(acc[i] + rr[i], 0.f));
      ov.x = p[0] | (p[1] << 16); ov.y = p[2] | (p[3] << 16);
      ov.z = p[4] | (p[5] << 16); ov.w = p[6] | (p[7] << 16);
      *(uint4*)(outb + (size_t)d * 256 + c * 8) = ov;
    }
  } else {
    #pragma unroll
    for (int i = 0; i < 8; ++i){
      float o = acc[i] + rr[i];
      o += __shfl_xor(o, 8);
      o += __shfl_xor(o, 16);
      acc[i] = o;
    }
    if (lane < 8){
      uint4 ov;
      unsigned p[8];
      #pragma unroll
      for (int i = 0; i < 8; ++i) p[i] = f2bf(0.25f * acc[i]);
      ov.x = p[0] | (p[1] << 16); ov.y = p[2] | (p[3] << 16);
      ov.z = p[4] | (p[5] << 16); ov.w = p[6] | (p[7] << 16);
      *(uint4*)(hf + (size_t)d * 64 + lane * 8) = ov;
    }
  }
}

// ---------------- MFMA edge MLP, CSR-ordered: 1 wave = 16 CSR slots -----------
// dst rows repeat across consecutive slots (L1/L2-warm); out scattered by eid.
__global__ __launch_bounds__(256) void edge_mlp_csr(
    const u16* __restrict__ hfb,
    const int* __restrict__ csr_src, const int* __restrict__ csr_dst,
    const int* __restrict__ csr_eid,
    const u16* __restrict__ Wm1, const u16* __restrict__ bm1,
    const u16* __restrict__ Wm2, const u16* __restrict__ bm2,
    void* __restrict__ out, int E, const int* __restrict__ flag)
{
  const int lane = threadIdx.x & 63;
  const int m = lane & 15;
  const int q = lane >> 4;
  const int is_f32 = *flag;

  bf16x8 bfr[4][2];
  #pragma unroll
  for (int t = 0; t < 4; ++t)
    #pragma unroll
    for (int ks = 0; ks < 2; ++ks)
      #pragma unroll
      for (int j = 0; j < 8; ++j)
        bfr[t][ks][j] = (short)Wm1[(size_t)(ks * 32 + q * 8 + j) * 64 + t * 16 + m];

  float b1v[4], w2v[4];
  #pragma unroll
  for (int t = 0; t < 4; ++t){
    b1v[t] = bf2f(bm1[t * 16 + m]);
    w2v[t] = bf2f(Wm2[t * 16 + m]);
  }
  const float b2 = bf2f(bm2[0]);

  const int wid = blockIdx.x * 4 + (threadIdx.x >> 6);
  const int nw  = gridDim.x * 4;
  for (int e0 = wid * 16; e0 < E; e0 += nw * 16){
    int e = e0 + m; if (e >= E) e = E - 1;
    const int s = csr_src[e], d = csr_dst[e];
    const u16* ps = hfb + (size_t)s * 64;
    const u16* pd = hfb + (size_t)d * 64;
    bf16x8 af[2];
    #pragma unroll
    for (int ks = 0; ks < 2; ++ks){
      bf16x8 vs = *(const bf16x8*)(ps + ks * 32 + q * 8);
      bf16x8 vd = *(const bf16x8*)(pd + ks * 32 + q * 8);
      #pragma unroll
      for (int j = 0; j < 8; ++j)
        af[ks][j] = (short)f2bf(fabsf(bf2f((u16)vs[j]) - bf2f((u16)vd[j])));
    }
    f32x4 acc[4];
    #pragma unroll
    for (int t = 0; t < 4; ++t) acc[t] = (f32x4){0.f, 0.f, 0.f, 0.f};
    #pragma unroll
    for (int ks = 0; ks < 2; ++ks)
      #pragma unroll
      for (int t = 0; t < 4; ++t)
        acc[t] = __builtin_amdgcn_mfma_f32_16x16x32_bf16(af[ks], bfr[t][ks], acc[t], 0, 0, 0);
    #pragma unroll
    for (int r = 0; r < 4; ++r){
      float p = 0.f;
      #pragma unroll
      for (int t = 0; t < 4; ++t)
        p += fmaxf(acc[t][r] + b1v[t], 0.f) * w2v[t];
      #pragma unroll
      for (int mm = 1; mm < 16; mm <<= 1) p += __shfl_xor(p, mm);
      int slot = e0 + q * 4 + r;
      if (m == 0 && slot < E){
        int eid = csr_eid[slot];
        float sc = 1.f / (1.f + __expf(-(p + b2)));
        if (is_f32) ((float*)out)[eid] = sc;
        else        ((u16*)out)[eid]   = f2bf(sc);
      }
    }
  }
}

extern "C" void kernel_launch(void* const* d_in, const int* in_sizes, int n_in,
                              void* d_out, int out_size, void* d_ws, size_t ws_size,
                              hipStream_t stream)
{
  const int* src = (const int*)d_in[1];
  const int* dst = (const int*)d_in[2];

  const int N = in_sizes[0] / 128;
  const int E = in_sizes[1];

  char* p = (char*)d_ws;
  auto alloc = [&](size_t bytes) -> char* {
    char* r = p; p += (bytes + 255) & ~(size_t)255; return r;
  };
  int* flag   = (int*)  alloc(4);
  u16* hc     = (u16*)  alloc((size_t)N * 128 * 2);
  u16* FT     = (u16*)  alloc((size_t)N * 256 * 2);
  u16* XA     = (u16*)  alloc((size_t)N * 256 * 2);
  u16* XB     = (u16*)  alloc((size_t)N * 256 * 2);
  float* el   = (float*)alloc((size_t)N * 4 * 4);
  float* er   = (float*)alloc((size_t)N * 4 * 4);
  u16* hfb    = (u16*)  alloc((size_t)N * 64 * 2);
  int* rowptr = (int*)  alloc((size_t)(N + 1) * 4);
  int* cursor = (int*)  alloc((size_t)N * 4);
  int* csr    = (int*)  alloc((size_t)E * 4);
  int* csrd   = (int*)  alloc((size_t)E * 4);
  int* csre   = (int*)  alloc((size_t)E * 4);
  int* bsums  = (int*)  alloc(1024);
  u16* WT1    = (u16*)  alloc(128 * 256 * 2);
  u16* WTr1   = (u16*)  alloc(128 * 256 * 2);
  u16* WT2    = (u16*)  alloc(256 * 256 * 2);
  u16* WT3    = (u16*)  alloc(256 * 256 * 2);
  u16* al1c   = (u16*)  alloc(256 * 2);
  u16* ar1c   = (u16*)  alloc(256 * 2);
  u16* al2c   = (u16*)  alloc(256 * 2);
  u16* ar2c   = (u16*)  alloc(256 * 2);
  u16* al3c   = (u16*)  alloc(256 * 2);
  u16* ar3c   = (u16*)  alloc(256 * 2);
  u16* Wm1c   = (u16*)  alloc(4096 * 2);
  u16* bm1c   = (u16*)  alloc(64 * 2);
  u16* Wm2c   = (u16*)  alloc(64 * 2);
  u16* bm2c   = (u16*)  alloc(2);

  const int nb = (N + 255) / 256;
  const int ge = (E + 255) / 256;

  // dtype sniff + canonicalize
  k_sniff<<<1, 256, 0, stream>>>((const u16*)d_in[0], flag);
  k_canon<<<(N * 128 + 255) / 256, 256, 0, stream>>>(d_in[0], hc, N * 128, flag);
  {
    Canon10 c;
    c.e[0] = {d_in[5],  al1c, 256};  c.e[1] = {d_in[6],  ar1c, 256};
    c.e[2] = {d_in[8],  al2c, 256};  c.e[3] = {d_in[9],  ar2c, 256};
    c.e[4] = {d_in[11], al3c, 256};  c.e[5] = {d_in[12], ar3c, 256};
    c.e[6] = {d_in[13], Wm1c, 4096}; c.e[7] = {d_in[14], bm1c, 64};
    c.e[8] = {d_in[15], Wm2c, 64};   c.e[9] = {d_in[16], bm2c, 1};
    dim3 g((4096 + 255) / 256, 10);
    k_canon10<<<g, 256, 0, stream>>>(c, flag);
  }
  {
    CanonW4 c;
    c.e[0] = {d_in[3],  WT1,  128};  c.e[1] = {d_in[4],  WTr1, 128};
    c.e[2] = {d_in[7],  WT2,  256};  c.e[3] = {d_in[10], WT3,  256};
    dim3 g(256, 4);
    k_canonw<<<g, 256, 0, stream>>>(c, flag);
  }

  // CSR by dst
  hipMemsetAsync(cursor, 0, (size_t)N * 4, stream);
  k_hist<<<ge, 256, 0, stream>>>(dst, cursor, E);
  k_scan1<<<nb, 256, 0, stream>>>(cursor, rowptr, bsums, N);
  k_scan2<<<1, 256, 0, stream>>>(bsums, nb);
  k_scan3<<<nb, 256, 0, stream>>>(rowptr, bsums, cursor, N);
  k_scatter<<<ge, 256, 0, stream>>>(src, dst, cursor, csr, csrd, csre, E);

  const int gA = (N + 127) / 128;
  const int gD = (N + 63) / 64;
  const int gG = (N + 3) / 4;
  // layer 1 (dual GEMM: FT + attn logits + residual XA)
  mfma_gemm_dual<<<gD, 256, 0, stream>>>(hc, WT1, WTr1, FT, XA, al1c, ar1c, el, er, N, 128);
  aggregate5<<<gG, 256, 0, stream>>>(FT, el, er, rowptr, csr, XA, XB, nullptr, 0, N);
  // layer 2
  mfma_gemm_attn2<<<gA, 256, 0, stream>>>(XB, WT2, FT, al2c, ar2c, el, er, N, 256);
  aggregate5<<<gG, 256, 0, stream>>>(FT, el, er, rowptr, csr, XB, XA, nullptr, 0, N);
  // layer 3 (fused head-mean -> hf bf16)
  mfma_gemm_attn2<<<gA, 256, 0, stream>>>(XA, WT3, FT, al3c, ar3c, el, er, N, 256);
  aggregate5<<<gG, 256, 0, stream>>>(FT, el, er, rowptr, csr, XA, nullptr, hfb, 1, N);
  // edge MLP (MFMA, CSR-ordered for dst-row locality)
  edge_mlp_csr<<<2048, 256, 0, stream>>>(hfb, csr, csrd, csre, Wm1c, bm1c, Wm2c, bm2c,
                                         d_out, E, flag);
}

// Round 8
// 661.100 us; speedup vs baseline: 1.0342x; 1.0342x over previous
//
#include <hip/hip_runtime.h>

typedef unsigned short u16;
typedef __attribute__((ext_vector_type(8))) short bf16x8;
typedef __attribute__((ext_vector_type(4))) float f32x4;

__device__ __forceinline__ float bf2f(u16 u){
  union { unsigned int i; float f; } v; v.i = ((unsigned int)u) << 16; return v.f;
}
__device__ __forceinline__ u16 f2bf(float f){
  union { float f; unsigned int i; } v; v.f = f;
  unsigned int lsb = (v.i >> 16) & 1u;
  v.i += 0x7fffu + lsb;
  return (u16)(v.i >> 16);
}
__device__ __forceinline__ void fma2(float& a0, float& a1, unsigned p, float s){
  union { unsigned u; float f; } lo, hi;
  lo.u = p << 16; hi.u = p & 0xffff0000u;
  a0 += s * lo.f; a1 += s * hi.f;
}

// ---------------- dtype sniffer ----------------
__global__ void k_sniff(const u16* __restrict__ p, int* __restrict__ flag){
  __shared__ int s[256];
  int tid = threadIdx.x;
  u16 v = p[2 * tid];
  int e = (v >> 7) & 0xFF;
  s[tid] = (e >= 100 && e <= 135) ? 1 : 0;
  __syncthreads();
  for (int off = 128; off; off >>= 1){
    if (tid < off) s[tid] += s[tid + off];
    __syncthreads();
  }
  if (tid == 0) *flag = (s[0] < 180) ? 1 : 0;
}
// vectorized canon (n divisible by 4)
__global__ void k_canon4(const void* __restrict__ src, u16* __restrict__ dst,
                         int n4, const int* __restrict__ flag){
  int i = blockIdx.x * 256 + threadIdx.x;
  if (i < n4){
    u16 o[4];
    if (*flag){
      float4 v = ((const float4*)src)[i];
      o[0] = f2bf(v.x); o[1] = f2bf(v.y); o[2] = f2bf(v.z); o[3] = f2bf(v.w);
    } else {
      uint2 v = ((const uint2*)src)[i];
      o[0] = (u16)v.x; o[1] = (u16)(v.x >> 16); o[2] = (u16)v.y; o[3] = (u16)(v.y >> 16);
    }
    uint2 w; w.x = o[0] | ((unsigned)o[1] << 16); w.y = o[2] | ((unsigned)o[3] << 16);
    ((uint2*)dst)[i] = w;
  }
}
struct CanonEnt { const void* s; u16* d; int n; };
struct Canon10 { CanonEnt e[10]; };
__global__ void k_canon10(Canon10 c, const int* __restrict__ flag){
  CanonEnt en = c.e[blockIdx.y];
  int i = blockIdx.x * 256 + threadIdx.x;
  if (i < en.n){
    if (*flag) en.d[i] = f2bf(((const float*)en.s)[i]);
    else       en.d[i] = ((const u16*)en.s)[i];
  }
}
struct CanonWEnt { const void* s; u16* wt; int K; };
struct CanonW4 { CanonWEnt e[4]; };
__global__ void k_canonw(CanonW4 c, const int* __restrict__ flag){
  CanonWEnt en = c.e[blockIdx.y];
  int i = blockIdx.x * 256 + threadIdx.x;
  if (i < 256 * en.K){
    int k = i >> 8, cc = i & 255;
    u16 b;
    if (*flag) b = f2bf(((const float*)en.s)[i]);
    else       b = ((const u16*)en.s)[i];
    en.wt[(size_t)cc * en.K + k] = b;
  }
}

// ---------------- CSR build ----------------
__global__ void k_hist(const int* __restrict__ dst, int* __restrict__ cnt, int E){
  int i = blockIdx.x * 256 + threadIdx.x;
  if (i < E) atomicAdd(&cnt[dst[i]], 1);
}
__global__ void k_scan1(const int* __restrict__ cnt, int* __restrict__ rowptr,
                        int* __restrict__ bsums, int N){
  __shared__ int s[256];
  int i = blockIdx.x * 256 + threadIdx.x;
  int v = (i < N) ? cnt[i] : 0;
  s[threadIdx.x] = v; __syncthreads();
  for (int off = 1; off < 256; off <<= 1){
    int x = 0;
    if (threadIdx.x >= off) x = s[threadIdx.x - off];
    __syncthreads();
    s[threadIdx.x] += x;
    __syncthreads();
  }
  if (i < N) rowptr[i + 1] = s[threadIdx.x];
  if (threadIdx.x == 255) bsums[blockIdx.x] = s[255];
}
__global__ void k_scan2(int* __restrict__ bsums, int nb){
  __shared__ int s[256];
  int t = threadIdx.x;
  int v = (t < nb) ? bsums[t] : 0;
  s[t] = v; __syncthreads();
  for (int off = 1; off < 256; off <<= 1){
    int x = 0;
    if (t >= off) x = s[t - off];
    __syncthreads();
    s[t] += x;
    __syncthreads();
  }
  if (t < nb) bsums[t] = s[t] - v;                // exclusive
}
__global__ void k_scan3(int* __restrict__ rowptr, const int* __restrict__ bsums,
                        int* __restrict__ cursor, int N){
  int i = blockIdx.x * 256 + threadIdx.x;
  if (i < N){
    int v = rowptr[i + 1] + bsums[blockIdx.x];
    rowptr[i + 1] = v;
    if (i + 1 < N) cursor[i + 1] = v;
    if (i == 0){ rowptr[0] = 0; cursor[0] = 0; }
  }
}
// packed CSR: one 16B store per edge {src, dst, eid, pad}
__global__ void k_scatter(const int* __restrict__ src, const int* __restrict__ dst,
                          int* __restrict__ cursor, int4* __restrict__ csrp, int E){
  int i = blockIdx.x * 256 + threadIdx.x;
  if (i < E){
    int p = atomicAdd(&cursor[dst[i]], 1);
    csrp[p] = make_int4(src[i], dst[i], i, 0);
  }
}

// ---------------- MFMA node GEMM v2: 32 rows/wave, 128 rows/block -------------
__global__ __launch_bounds__(256) void mfma_gemm2(
    const u16* __restrict__ X, const u16* __restrict__ WT,
    u16* __restrict__ OUT, int N, int K)
{
  const int wave = threadIdx.x >> 6;
  const int lane = threadIdx.x & 63;
  const int m = lane & 15;
  const int q = lane >> 4;
  const int row0 = blockIdx.x * 128 + wave * 32;
  f32x4 acc[2][16];
  #pragma unroll
  for (int g = 0; g < 2; ++g)
    #pragma unroll
    for (int t = 0; t < 16; ++t) acc[g][t] = (f32x4){0.f, 0.f, 0.f, 0.f};
  const int rA = row0 + m, rB = row0 + 16 + m;
  const bool vA = rA < N, vB = rB < N;
  const u16* apA = X + (size_t)rA * K + q * 8;
  const u16* apB = X + (size_t)rB * K + q * 8;
  for (int k0 = 0; k0 < K; k0 += 32){
    bf16x8 aA = {}, aB = {};
    if (vA) aA = *(const bf16x8*)(apA + k0);
    if (vB) aB = *(const bf16x8*)(apB + k0);
    #pragma unroll
    for (int t = 0; t < 16; ++t){
      const u16* bptr = WT + (size_t)(t * 16 + m) * K + k0 + q * 8;
      bf16x8 b = *(const bf16x8*)bptr;
      acc[0][t] = __builtin_amdgcn_mfma_f32_16x16x32_bf16(aA, b, acc[0][t], 0, 0, 0);
      acc[1][t] = __builtin_amdgcn_mfma_f32_16x16x32_bf16(aB, b, acc[1][t], 0, 0, 0);
    }
  }
  #pragma unroll
  for (int g = 0; g < 2; ++g)
    #pragma unroll
    for (int t = 0; t < 16; ++t){
      int col = t * 16 + m;
      #pragma unroll
      for (int r = 0; r < 4; ++r){
        int rr = row0 + g * 16 + q * 4 + r;
        if (rr < N) OUT[(size_t)rr * 256 + col] = f2bf(acc[g][t][r]);
      }
    }
}

// ---------------- MFMA node GEMM v2 + fused attention logits ------------------
__global__ __launch_bounds__(256) void mfma_gemm_attn2(
    const u16* __restrict__ X, const u16* __restrict__ WT,
    u16* __restrict__ OUT, const u16* __restrict__ al, const u16* __restrict__ ar,
    float* __restrict__ el4, float* __restrict__ er4, int N, int K)
{
  const int wave = threadIdx.x >> 6;
  const int lane = threadIdx.x & 63;
  const int m = lane & 15;
  const int q = lane >> 4;
  const int row0 = blockIdx.x * 128 + wave * 32;
  f32x4 acc[2][16];
  #pragma unroll
  for (int g = 0; g < 2; ++g)
    #pragma unroll
    for (int t = 0; t < 16; ++t) acc[g][t] = (f32x4){0.f, 0.f, 0.f, 0.f};
  const int rA = row0 + m, rB = row0 + 16 + m;
  const bool vA = rA < N, vB = rB < N;
  const u16* apA = X + (size_t)rA * K + q * 8;
  const u16* apB = X + (size_t)rB * K + q * 8;
  for (int k0 = 0; k0 < K; k0 += 32){
    bf16x8 aA = {}, aB = {};
    if (vA) aA = *(const bf16x8*)(apA + k0);
    if (vB) aB = *(const bf16x8*)(apB + k0);
    #pragma unroll
    for (int t = 0; t < 16; ++t){
      const u16* bptr = WT + (size_t)(t * 16 + m) * K + k0 + q * 8;
      bf16x8 b = *(const bf16x8*)bptr;
      acc[0][t] = __builtin_amdgcn_mfma_f32_16x16x32_bf16(aA, b, acc[0][t], 0, 0, 0);
      acc[1][t] = __builtin_amdgcn_mfma_f32_16x16x32_bf16(aB, b, acc[1][t], 0, 0, 0);
    }
  }
  // attn vectors loaded after the K-loop (keeps loop-live VGPRs low)
  float alv[16], arv[16];
  #pragma unroll
  for (int t = 0; t < 16; ++t){
    alv[t] = bf2f(al[t * 16 + m]);
    arv[t] = bf2f(ar[t * 16 + m]);
  }
  #pragma unroll
  for (int g = 0; g < 2; ++g)
    #pragma unroll
    for (int r = 0; r < 4; ++r){
      float pe[4] = {0.f, 0.f, 0.f, 0.f}, pr[4] = {0.f, 0.f, 0.f, 0.f};
      #pragma unroll
      for (int t = 0; t < 16; ++t){
        pe[t >> 2] += acc[g][t][r] * alv[t];
        pr[t >> 2] += acc[g][t][r] * arv[t];
      }
      #pragma unroll
      for (int mk = 1; mk < 16; mk <<= 1){
        #pragma unroll
        for (int hh = 0; hh < 4; ++hh){
          pe[hh] += __shfl_xor(pe[hh], mk);
          pr[hh] += __shfl_xor(pr[hh], mk);
        }
      }
      int rr = row0 + g * 16 + q * 4 + r;
      if (m == 0 && rr < N){
        *(f32x4*)(el4 + (size_t)rr * 4) = (f32x4){pe[0], pe[1], pe[2], pe[3]};
        *(f32x4*)(er4 + (size_t)rr * 4) = (f32x4){pr[0], pr[1], pr[2], pr[3]};
      }
    }
  #pragma unroll
  for (int g = 0; g < 2; ++g)
    #pragma unroll
    for (int t = 0; t < 16; ++t){
      int col = t * 16 + m;
      #pragma unroll
      for (int r = 0; r < 4; ++r){
        int rr = row0 + g * 16 + q * 4 + r;
        if (rr < N) OUT[(size_t)rr * 256 + col] = f2bf(acc[g][t][r]);
      }
    }
}

// ---------------- aggregation v5: 1 wave = 1 dst, 16B/lane, 4 edges batched ---
__global__ __launch_bounds__(256) void aggregate5(
    const u16* __restrict__ ft, const float* __restrict__ el4, const float* __restrict__ er4,
    const int* __restrict__ rowptr, const int4* __restrict__ csrp,
    const u16* __restrict__ residb, u16* __restrict__ outb,
    u16* __restrict__ hf, int do_hf, int N)
{
  __shared__ float sal[4][64][4];
  __shared__ int   sof[4][64];
  const int w = threadIdx.x >> 6, lane = threadIdx.x & 63;
  const int d = blockIdx.x * 4 + w;
  if (d >= N) return;
  const int beg = rowptr[d], deg = rowptr[d + 1] - beg;
  const int H = lane >> 5;            // edge-parity half
  const int c = lane & 31;            // col group: cols c*8 .. c*8+7
  const int hg = c >> 3;              // head of those cols
  float acc[8] = {0.f, 0.f, 0.f, 0.f, 0.f, 0.f, 0.f, 0.f};

  if (deg > 0){
    const float4 erd = ((const float4*)er4)[d];
    const int dc = min(deg, 64);
    float m0 = -3.0e38f, m1 = -3.0e38f, m2 = -3.0e38f, m3 = -3.0e38f;
    float ec0 = 0.f, ec1 = 0.f, ec2 = 0.f, ec3 = 0.f; int sc = 0;
    for (int j = lane; j < deg; j += 64){
      int s = csrp[beg + j].x;
      float4 ql = ((const float4*)el4)[s];
      float e0 = ql.x + erd.x; e0 = (e0 > 0.f) ? e0 : 0.2f * e0;
      float e1 = ql.y + erd.y; e1 = (e1 > 0.f) ? e1 : 0.2f * e1;
      float e2 = ql.z + erd.z; e2 = (e2 > 0.f) ? e2 : 0.2f * e2;
      float e3 = ql.w + erd.w; e3 = (e3 > 0.f) ? e3 : 0.2f * e3;
      if (j < 64){ ec0 = e0; ec1 = e1; ec2 = e2; ec3 = e3; sc = s; }
      m0 = fmaxf(m0, e0); m1 = fmaxf(m1, e1);
      m2 = fmaxf(m2, e2); m3 = fmaxf(m3, e3);
    }
    for (int mk = 1; mk < dc; mk <<= 1){
      m0 = fmaxf(m0, __shfl_xor(m0, mk)); m1 = fmaxf(m1, __shfl_xor(m1, mk));
      m2 = fmaxf(m2, __shfl_xor(m2, mk)); m3 = fmaxf(m3, __shfl_xor(m3, mk));
    }
    float x0 = 0.f, x1 = 0.f, x2 = 0.f, x3 = 0.f;
    float d0 = 0.f, d1 = 0.f, d2 = 0.f, d3 = 0.f;
    for (int j = lane; j < deg; j += 64){
      float e0, e1, e2, e3;
      if (j < 64){ e0 = ec0; e1 = ec1; e2 = ec2; e3 = ec3; }
      else {
        int s = csrp[beg + j].x;
        float4 ql = ((const float4*)el4)[s];
        e0 = ql.x + erd.x; e0 = (e0 > 0.f) ? e0 : 0.2f * e0;
        e1 = ql.y + erd.y; e1 = (e1 > 0.f) ? e1 : 0.2f * e1;
        e2 = ql.z + erd.z; e2 = (e2 > 0.f) ? e2 : 0.2f * e2;
        e3 = ql.w + erd.w; e3 = (e3 > 0.f) ? e3 : 0.2f * e3;
      }
      float t0 = __expf(e0 - m0), t1 = __expf(e1 - m1);
      float t2 = __expf(e2 - m2), t3 = __expf(e3 - m3);
      if (j < 64){ x0 = t0; x1 = t1; x2 = t2; x3 = t3; }
      d0 += t0; d1 += t1; d2 += t2; d3 += t3;
    }
    for (int mk = 1; mk < dc; mk <<= 1){
      d0 += __shfl_xor(d0, mk); d1 += __shfl_xor(d1, mk);
      d2 += __shfl_xor(d2, mk); d3 += __shfl_xor(d3, mk);
    }
    const float i0 = 1.f / d0, i1 = 1.f / d1, i2 = 1.f / d2, i3 = 1.f / d3;

    for (int c0 = 0; c0 < deg; c0 += 64){
      int cs = min(64, deg - c0);
      if (lane < cs){
        float t0, t1, t2, t3; int s;
        if (c0 == 0){ t0 = x0; t1 = x1; t2 = x2; t3 = x3; s = sc; }
        else {
          s = csrp[beg + c0 + lane].x;
          float4 ql = ((const float4*)el4)[s];
          float e0 = ql.x + erd.x; e0 = (e0 > 0.f) ? e0 : 0.2f * e0;
          float e1 = ql.y + erd.y; e1 = (e1 > 0.f) ? e1 : 0.2f * e1;
          float e2 = ql.z + erd.z; e2 = (e2 > 0.f) ? e2 : 0.2f * e2;
          float e3 = ql.w + erd.w; e3 = (e3 > 0.f) ? e3 : 0.2f * e3;
          t0 = __expf(e0 - m0); t1 = __expf(e1 - m1);
          t2 = __expf(e2 - m2); t3 = __expf(e3 - m3);
        }
        sal[w][lane][0] = t0 * i0; sal[w][lane][1] = t1 * i1;
        sal[w][lane][2] = t2 * i2; sal[w][lane][3] = t3 * i3;
        sof[w][lane] = s << 9;                      // s * 512 bytes
      }
      __builtin_amdgcn_wave_barrier();
      for (int j0 = 0; j0 < cs; j0 += 4){
        int jA = j0 + H, jB = j0 + 2 + H;
        bool bA = jA < cs, bB = jB < cs;
        float aA = 0.f, aB = 0.f;
        int offA = 0, offB = 0;
        if (bA){ aA = sal[w][jA][hg]; offA = sof[w][jA]; }
        if (bB){ aB = sal[w][jB][hg]; offB = sof[w][jB]; }
        uint4 vA = {}, vB = {};
        if (bA) vA = *(const uint4*)((const char*)ft + (size_t)(unsigned)offA + c * 16);
        if (bB) vB = *(const uint4*)((const char*)ft + (size_t)(unsigned)offB + c * 16);
        if (bA){
          fma2(acc[0], acc[1], vA.x, aA);
          fma2(acc[2], acc[3], vA.y, aA);
          fma2(acc[4], acc[5], vA.z, aA);
          fma2(acc[6], acc[7], vA.w, aA);
        }
        if (bB){
          fma2(acc[0], acc[1], vB.x, aB);
          fma2(acc[2], acc[3], vB.y, aB);
          fma2(acc[4], acc[5], vB.z, aB);
          fma2(acc[6], acc[7], vB.w, aB);
        }
      }
      __builtin_amdgcn_wave_barrier();
    }
  }
  // combine the two edge-parity halves
  #pragma unroll
  for (int i = 0; i < 8; ++i) acc[i] += __shfl_xor(acc[i], 32);
  uint4 rv = *(const uint4*)(residb + (size_t)d * 256 + c * 8);
  float rr[8];
  {
    union { unsigned u; float f; } t;
    t.u = rv.x << 16; rr[0] = t.f; t.u = rv.x & 0xffff0000u; rr[1] = t.f;
    t.u = rv.y << 16; rr[2] = t.f; t.u = rv.y & 0xffff0000u; rr[3] = t.f;
    t.u = rv.z << 16; rr[4] = t.f; t.u = rv.z & 0xffff0000u; rr[5] = t.f;
    t.u = rv.w << 16; rr[6] = t.f; t.u = rv.w & 0xffff0000u; rr[7] = t.f;
  }
  if (!do_hf){
    if (H == 0){
      uint4 ov;
      unsigned p[8];
      #pragma unroll
      for (int i = 0; i < 8; ++i) p[i] = f2bf(fmaxf(acc[i] + rr[i], 0.f));
      ov.x = p[0] | (p[1] << 16); ov.y = p[2] | (p[3] << 16);
      ov.z = p[4] | (p[5] << 16); ov.w = p[6] | (p[7] << 16);
      *(uint4*)(outb + (size_t)d * 256 + c * 8) = ov;
    }
  } else {
    #pragma unroll
    for (int i = 0; i < 8; ++i){
      float o = acc[i] + rr[i];
      o += __shfl_xor(o, 8);
      o += __shfl_xor(o, 16);
      acc[i] = o;
    }
    if (lane < 8){
      uint4 ov;
      unsigned p[8];
      #pragma unroll
      for (int i = 0; i < 8; ++i) p[i] = f2bf(0.25f * acc[i]);
      ov.x = p[0] | (p[1] << 16); ov.y = p[2] | (p[3] << 16);
      ov.z = p[4] | (p[5] << 16); ov.w = p[6] | (p[7] << 16);
      *(uint4*)(hf + (size_t)d * 64 + lane * 8) = ov;
    }
  }
}

// ---------------- MFMA edge MLP, CSR-ordered: 1 wave = 16 CSR slots -----------
// dst rows repeat across consecutive slots (L1/L2-warm); out scattered by eid.
__global__ __launch_bounds__(256) void edge_mlp_csr(
    const u16* __restrict__ hfb, const int4* __restrict__ csrp,
    const u16* __restrict__ Wm1, const u16* __restrict__ bm1,
    const u16* __restrict__ Wm2, const u16* __restrict__ bm2,
    void* __restrict__ out, int E, const int* __restrict__ flag)
{
  const int lane = threadIdx.x & 63;
  const int m = lane & 15;
  const int q = lane >> 4;
  const int is_f32 = *flag;

  bf16x8 bfr[4][2];
  #pragma unroll
  for (int t = 0; t < 4; ++t)
    #pragma unroll
    for (int ks = 0; ks < 2; ++ks)
      #pragma unroll
      for (int j = 0; j < 8; ++j)
        bfr[t][ks][j] = (short)Wm1[(size_t)(ks * 32 + q * 8 + j) * 64 + t * 16 + m];

  float b1v[4], w2v[4];
  #pragma unroll
  for (int t = 0; t < 4; ++t){
    b1v[t] = bf2f(bm1[t * 16 + m]);
    w2v[t] = bf2f(Wm2[t * 16 + m]);
  }
  const float b2 = bf2f(bm2[0]);

  const int wid = blockIdx.x * 4 + (threadIdx.x >> 6);
  const int nw  = gridDim.x * 4;
  for (int e0 = wid * 16; e0 < E; e0 += nw * 16){
    int e = e0 + m; if (e >= E) e = E - 1;
    int4 ed = csrp[e];
    const u16* ps = hfb + (size_t)ed.x * 64;
    const u16* pd = hfb + (size_t)ed.y * 64;
    bf16x8 af[2];
    #pragma unroll
    for (int ks = 0; ks < 2; ++ks){
      bf16x8 vs = *(const bf16x8*)(ps + ks * 32 + q * 8);
      bf16x8 vd = *(const bf16x8*)(pd + ks * 32 + q * 8);
      #pragma unroll
      for (int j = 0; j < 8; ++j)
        af[ks][j] = (short)f2bf(fabsf(bf2f((u16)vs[j]) - bf2f((u16)vd[j])));
    }
    f32x4 acc[4];
    #pragma unroll
    for (int t = 0; t < 4; ++t) acc[t] = (f32x4){0.f, 0.f, 0.f, 0.f};
    #pragma unroll
    for (int ks = 0; ks < 2; ++ks)
      #pragma unroll
      for (int t = 0; t < 4; ++t)
        acc[t] = __builtin_amdgcn_mfma_f32_16x16x32_bf16(af[ks], bfr[t][ks], acc[t], 0, 0, 0);
    #pragma unroll
    for (int r = 0; r < 4; ++r){
      float p = 0.f;
      #pragma unroll
      for (int t = 0; t < 4; ++t)
        p += fmaxf(acc[t][r] + b1v[t], 0.f) * w2v[t];
      #pragma unroll
      for (int mm = 1; mm < 16; mm <<= 1) p += __shfl_xor(p, mm);
      int slot = e0 + q * 4 + r;
      if (m == 0 && slot < E){
        int eid = csrp[slot].z;
        float sc = 1.f / (1.f + __expf(-(p + b2)));
        if (is_f32) ((float*)out)[eid] = sc;
        else        ((u16*)out)[eid]   = f2bf(sc);
      }
    }
  }
}

extern "C" void kernel_launch(void* const* d_in, const int* in_sizes, int n_in,
                              void* d_out, int out_size, void* d_ws, size_t ws_size,
                              hipStream_t stream)
{
  const int* src = (const int*)d_in[1];
  const int* dst = (const int*)d_in[2];

  const int N = in_sizes[0] / 128;
  const int E = in_sizes[1];

  char* p = (char*)d_ws;
  auto alloc = [&](size_t bytes) -> char* {
    char* r = p; p += (bytes + 255) & ~(size_t)255; return r;
  };
  int* flag   = (int*)  alloc(4);
  u16* hc     = (u16*)  alloc((size_t)N * 128 * 2);
  u16* FT     = (u16*)  alloc((size_t)N * 256 * 2);
  u16* XA     = (u16*)  alloc((size_t)N * 256 * 2);
  u16* XB     = (u16*)  alloc((size_t)N * 256 * 2);
  float* el   = (float*)alloc((size_t)N * 4 * 4);
  float* er   = (float*)alloc((size_t)N * 4 * 4);
  u16* hfb    = (u16*)  alloc((size_t)N * 64 * 2);
  int* rowptr = (int*)  alloc((size_t)(N + 1) * 4);
  int* cursor = (int*)  alloc((size_t)N * 4);
  int4* csrp  = (int4*) alloc((size_t)E * 16);
  int* bsums  = (int*)  alloc(1024);
  u16* WT1    = (u16*)  alloc(128 * 256 * 2);
  u16* WTr1   = (u16*)  alloc(128 * 256 * 2);
  u16* WT2    = (u16*)  alloc(256 * 256 * 2);
  u16* WT3    = (u16*)  alloc(256 * 256 * 2);
  u16* al1c   = (u16*)  alloc(256 * 2);
  u16* ar1c   = (u16*)  alloc(256 * 2);
  u16* al2c   = (u16*)  alloc(256 * 2);
  u16* ar2c   = (u16*)  alloc(256 * 2);
  u16* al3c   = (u16*)  alloc(256 * 2);
  u16* ar3c   = (u16*)  alloc(256 * 2);
  u16* Wm1c   = (u16*)  alloc(4096 * 2);
  u16* bm1c   = (u16*)  alloc(64 * 2);
  u16* Wm2c   = (u16*)  alloc(64 * 2);
  u16* bm2c   = (u16*)  alloc(2);

  const int nb = (N + 255) / 256;
  const int ge = (E + 255) / 256;

  // dtype sniff + canonicalize
  k_sniff<<<1, 256, 0, stream>>>((const u16*)d_in[0], flag);
  k_canon4<<<(N * 32 + 255) / 256, 256, 0, stream>>>(d_in[0], hc, N * 32, flag);
  {
    Canon10 c;
    c.e[0] = {d_in[5],  al1c, 256};  c.e[1] = {d_in[6],  ar1c, 256};
    c.e[2] = {d_in[8],  al2c, 256};  c.e[3] = {d_in[9],  ar2c, 256};
    c.e[4] = {d_in[11], al3c, 256};  c.e[5] = {d_in[12], ar3c, 256};
    c.e[6] = {d_in[13], Wm1c, 4096}; c.e[7] = {d_in[14], bm1c, 64};
    c.e[8] = {d_in[15], Wm2c, 64};   c.e[9] = {d_in[16], bm2c, 1};
    dim3 g((4096 + 255) / 256, 10);
    k_canon10<<<g, 256, 0, stream>>>(c, flag);
  }
  {
    CanonW4 c;
    c.e[0] = {d_in[3],  WT1,  128};  c.e[1] = {d_in[4],  WTr1, 128};
    c.e[2] = {d_in[7],  WT2,  256};  c.e[3] = {d_in[10], WT3,  256};
    dim3 g(256, 4);
    k_canonw<<<g, 256, 0, stream>>>(c, flag);
  }

  // CSR by dst
  hipMemsetAsync(cursor, 0, (size_t)N * 4, stream);
  k_hist<<<ge, 256, 0, stream>>>(dst, cursor, E);
  k_scan1<<<nb, 256, 0, stream>>>(cursor, rowptr, bsums, N);
  k_scan2<<<1, 256, 0, stream>>>(bsums, nb);
  k_scan3<<<nb, 256, 0, stream>>>(rowptr, bsums, cursor, N);
  k_scatter<<<ge, 256, 0, stream>>>(src, dst, cursor, csrp, E);

  const int gA = (N + 127) / 128;
  const int gG = (N + 3) / 4;
  // layer 1
  mfma_gemm_attn2<<<gA, 256, 0, stream>>>(hc, WT1, FT, al1c, ar1c, el, er, N, 128);
  mfma_gemm2<<<gA, 256, 0, stream>>>(hc, WTr1, XA, N, 128);
  aggregate5<<<gG, 256, 0, stream>>>(FT, el, er, rowptr, csrp, XA, XB, nullptr, 0, N);
  // layer 2
  mfma_gemm_attn2<<<gA, 256, 0, stream>>>(XB, WT2, FT, al2c, ar2c, el, er, N, 256);
  aggregate5<<<gG, 256, 0, stream>>>(FT, el, er, rowptr, csrp, XB, XA, nullptr, 0, N);
  // layer 3 (fused head-mean -> hf bf16)
  mfma_gemm_attn2<<<gA, 256, 0, stream>>>(XA, WT3, FT, al3c, ar3c, el, er, N, 256);
  aggregate5<<<gG, 256, 0, stream>>>(FT, el, er, rowptr, csrp, XA, nullptr, hfb, 1, N);
  // edge MLP (MFMA, CSR-ordered for dst-row locality)
  edge_mlp_csr<<<2048, 256, 0, stream>>>(hfb, csrp, Wm1c, bm1c, Wm2c, bm2c,
                                         d_out, E, flag);
}

// Round 9
// 602.021 us; speedup vs baseline: 1.1357x; 1.0981x over previous
//
#include <hip/hip_runtime.h>
#include <hip/hip_bf16.h>

typedef unsigned short u16;
typedef __attribute__((ext_vector_type(8))) short bf16x8;
typedef __attribute__((ext_vector_type(4))) float f32x4;

__device__ __forceinline__ float bf2f(u16 u){
  union { unsigned int i; float f; } v; v.i = ((unsigned int)u) << 16; return v.f;
}
__device__ __forceinline__ u16 f2bf(float f){
  union { float f; unsigned int i; } v; v.f = f;
  unsigned int lsb = (v.i >> 16) & 1u;
  v.i += 0x7fffu + lsb;
  return (u16)(v.i >> 16);
}
__device__ __forceinline__ unsigned pkbf(float a, float b){
  __hip_bfloat162 h = __float22bfloat162_rn(make_float2(a, b));
  union { __hip_bfloat162 h2; unsigned u; } c; c.h2 = h; return c.u;
}
__device__ __forceinline__ void fma2(float& a0, float& a1, unsigned p, float s){
  union { unsigned u; float f; } lo, hi;
  lo.u = p << 16; hi.u = p & 0xffff0000u;
  a0 += s * lo.f; a1 += s * hi.f;
}

// ---------------- dtype sniffer ----------------
__global__ void k_sniff(const u16* __restrict__ p, int* __restrict__ flag){
  __shared__ int s[256];
  int tid = threadIdx.x;
  u16 v = p[2 * tid];
  int e = (v >> 7) & 0xFF;
  s[tid] = (e >= 100 && e <= 135) ? 1 : 0;
  __syncthreads();
  for (int off = 128; off; off >>= 1){
    if (tid < off) s[tid] += s[tid + off];
    __syncthreads();
  }
  if (tid == 0) *flag = (s[0] < 180) ? 1 : 0;
}
__global__ void k_canon4(const void* __restrict__ src, u16* __restrict__ dst,
                         int n4, const int* __restrict__ flag){
  int i = blockIdx.x * 256 + threadIdx.x;
  if (i < n4){
    u16 o[4];
    if (*flag){
      float4 v = ((const float4*)src)[i];
      o[0] = f2bf(v.x); o[1] = f2bf(v.y); o[2] = f2bf(v.z); o[3] = f2bf(v.w);
    } else {
      uint2 v = ((const uint2*)src)[i];
      o[0] = (u16)v.x; o[1] = (u16)(v.x >> 16); o[2] = (u16)v.y; o[3] = (u16)(v.y >> 16);
    }
    uint2 w; w.x = o[0] | ((unsigned)o[1] << 16); w.y = o[2] | ((unsigned)o[3] << 16);
    ((uint2*)dst)[i] = w;
  }
}
struct CanonEnt { const void* s; u16* d; int n; };
struct Canon10 { CanonEnt e[10]; };
__global__ void k_canon10(Canon10 c, const int* __restrict__ flag){
  CanonEnt en = c.e[blockIdx.y];
  int i = blockIdx.x * 256 + threadIdx.x;
  if (i < en.n){
    if (*flag) en.d[i] = f2bf(((const float*)en.s)[i]);
    else       en.d[i] = ((const u16*)en.s)[i];
  }
}
struct CanonWEnt { const void* s; u16* wt; int K; };
struct CanonW4 { CanonWEnt e[4]; };
__global__ void k_canonw(CanonW4 c, const int* __restrict__ flag){
  CanonWEnt en = c.e[blockIdx.y];
  int i = blockIdx.x * 256 + threadIdx.x;
  if (i < 256 * en.K){
    int k = i >> 8, cc = i & 255;
    u16 b;
    if (*flag) b = f2bf(((const float*)en.s)[i]);
    else       b = ((const u16*)en.s)[i];
    en.wt[(size_t)cc * en.K + k] = b;
  }
}

// ---------------- CSR build ----------------
__global__ void k_hist(const int* __restrict__ dst, int* __restrict__ cnt, int E){
  int i = blockIdx.x * 256 + threadIdx.x;
  if (i < E) atomicAdd(&cnt[dst[i]], 1);
}
__global__ void k_scan1(const int* __restrict__ cnt, int* __restrict__ rowptr,
                        int* __restrict__ bsums, int N){
  __shared__ int s[256];
  int i = blockIdx.x * 256 + threadIdx.x;
  int v = (i < N) ? cnt[i] : 0;
  s[threadIdx.x] = v; __syncthreads();
  for (int off = 1; off < 256; off <<= 1){
    int x = 0;
    if (threadIdx.x >= off) x = s[threadIdx.x - off];
    __syncthreads();
    s[threadIdx.x] += x;
    __syncthreads();
  }
  if (i < N) rowptr[i + 1] = s[threadIdx.x];
  if (threadIdx.x == 255) bsums[blockIdx.x] = s[255];
}
__global__ void k_scan2(int* __restrict__ bsums, int nb){
  __shared__ int s[256];
  int t = threadIdx.x;
  int v = (t < nb) ? bsums[t] : 0;
  s[t] = v; __syncthreads();
  for (int off = 1; off < 256; off <<= 1){
    int x = 0;
    if (t >= off) x = s[t - off];
    __syncthreads();
    s[t] += x;
    __syncthreads();
  }
  if (t < nb) bsums[t] = s[t] - v;                // exclusive
}
__global__ void k_scan3(int* __restrict__ rowptr, const int* __restrict__ bsums,
                        int* __restrict__ cursor, int N){
  int i = blockIdx.x * 256 + threadIdx.x;
  if (i < N){
    int v = rowptr[i + 1] + bsums[blockIdx.x];
    rowptr[i + 1] = v;
    if (i + 1 < N) cursor[i + 1] = v;
    if (i == 0){ rowptr[0] = 0; cursor[0] = 0; }
  }
}
__global__ void k_scatter(const int* __restrict__ src, const int* __restrict__ dst,
                          int* __restrict__ cursor, int4* __restrict__ csrp, int E){
  int i = blockIdx.x * 256 + threadIdx.x;
  if (i < E){
    int p = atomicAdd(&cursor[dst[i]], 1);
    csrp[p] = make_int4(src[i], dst[i], i, 0);
  }
}

// ---------------- MFMA node GEMM v3: column-split x2 --------------------------
// grid (rows/128, 2). Block: 4 waves x (32 rows x 128 cols). acc = 64 VGPR.
__global__ __launch_bounds__(256, 4) void mfma_gemm3(
    const u16* __restrict__ X, const u16* __restrict__ WT,
    u16* __restrict__ OUT, int N, int K)
{
  const int wave = threadIdx.x >> 6;
  const int lane = threadIdx.x & 63;
  const int m = lane & 15;
  const int q = lane >> 4;
  const int row0 = blockIdx.x * 128 + wave * 32;
  const int col0 = blockIdx.y * 128;
  f32x4 acc[2][8];
  #pragma unroll
  for (int g = 0; g < 2; ++g)
    #pragma unroll
    for (int t = 0; t < 8; ++t) acc[g][t] = (f32x4){0.f, 0.f, 0.f, 0.f};
  const int rA = row0 + m, rB = row0 + 16 + m;
  const bool vA = rA < N, vB = rB < N;
  const u16* apA = X + (size_t)rA * K + q * 8;
  const u16* apB = X + (size_t)rB * K + q * 8;
  for (int k0 = 0; k0 < K; k0 += 32){
    bf16x8 aA = {}, aB = {};
    if (vA) aA = *(const bf16x8*)(apA + k0);
    if (vB) aB = *(const bf16x8*)(apB + k0);
    #pragma unroll
    for (int t = 0; t < 8; ++t){
      const u16* bptr = WT + (size_t)(col0 + t * 16 + m) * K + k0 + q * 8;
      bf16x8 b = *(const bf16x8*)bptr;
      acc[0][t] = __builtin_amdgcn_mfma_f32_16x16x32_bf16(aA, b, acc[0][t], 0, 0, 0);
      acc[1][t] = __builtin_amdgcn_mfma_f32_16x16x32_bf16(aB, b, acc[1][t], 0, 0, 0);
    }
  }
  #pragma unroll
  for (int g = 0; g < 2; ++g)
    #pragma unroll
    for (int t = 0; t < 8; ++t){
      int col = col0 + t * 16 + m;
      #pragma unroll
      for (int r = 0; r < 4; ++r){
        int rr = row0 + g * 16 + q * 4 + r;
        if (rr < N) OUT[(size_t)rr * 256 + col] = f2bf(acc[g][t][r]);
      }
    }
}

// ---------------- GEMM v3 + fused attention logits (2 heads per block) --------
__global__ __launch_bounds__(256, 4) void mfma_gemm_attn3(
    const u16* __restrict__ X, const u16* __restrict__ WT,
    u16* __restrict__ OUT, const u16* __restrict__ al, const u16* __restrict__ ar,
    float* __restrict__ el4, float* __restrict__ er4, int N, int K)
{
  const int wave = threadIdx.x >> 6;
  const int lane = threadIdx.x & 63;
  const int m = lane & 15;
  const int q = lane >> 4;
  const int row0 = blockIdx.x * 128 + wave * 32;
  const int col0 = blockIdx.y * 128;
  f32x4 acc[2][8];
  #pragma unroll
  for (int g = 0; g < 2; ++g)
    #pragma unroll
    for (int t = 0; t < 8; ++t) acc[g][t] = (f32x4){0.f, 0.f, 0.f, 0.f};
  const int rA = row0 + m, rB = row0 + 16 + m;
  const bool vA = rA < N, vB = rB < N;
  const u16* apA = X + (size_t)rA * K + q * 8;
  const u16* apB = X + (size_t)rB * K + q * 8;
  for (int k0 = 0; k0 < K; k0 += 32){
    bf16x8 aA = {}, aB = {};
    if (vA) aA = *(const bf16x8*)(apA + k0);
    if (vB) aB = *(const bf16x8*)(apB + k0);
    #pragma unroll
    for (int t = 0; t < 8; ++t){
      const u16* bptr = WT + (size_t)(col0 + t * 16 + m) * K + k0 + q * 8;
      bf16x8 b = *(const bf16x8*)bptr;
      acc[0][t] = __builtin_amdgcn_mfma_f32_16x16x32_bf16(aA, b, acc[0][t], 0, 0, 0);
      acc[1][t] = __builtin_amdgcn_mfma_f32_16x16x32_bf16(aB, b, acc[1][t], 0, 0, 0);
    }
  }
  // attn vectors for this block's 2 heads (cols col0..col0+127)
  float alv[8], arv[8];
  #pragma unroll
  for (int t = 0; t < 8; ++t){
    alv[t] = bf2f(al[col0 + t * 16 + m]);
    arv[t] = bf2f(ar[col0 + t * 16 + m]);
  }
  #pragma unroll
  for (int g = 0; g < 2; ++g)
    #pragma unroll
    for (int r = 0; r < 4; ++r){
      float pe[2] = {0.f, 0.f}, pr[2] = {0.f, 0.f};
      #pragma unroll
      for (int t = 0; t < 8; ++t){
        pe[t >> 2] += acc[g][t][r] * alv[t];
        pr[t >> 2] += acc[g][t][r] * arv[t];
      }
      #pragma unroll
      for (int mk = 1; mk < 16; mk <<= 1){
        pe[0] += __shfl_xor(pe[0], mk); pe[1] += __shfl_xor(pe[1], mk);
        pr[0] += __shfl_xor(pr[0], mk); pr[1] += __shfl_xor(pr[1], mk);
      }
      int rr = row0 + g * 16 + q * 4 + r;
      if (m == 0 && rr < N){
        *(float2*)(el4 + (size_t)rr * 4 + blockIdx.y * 2) = make_float2(pe[0], pe[1]);
        *(float2*)(er4 + (size_t)rr * 4 + blockIdx.y * 2) = make_float2(pr[0], pr[1]);
      }
    }
  #pragma unroll
  for (int g = 0; g < 2; ++g)
    #pragma unroll
    for (int t = 0; t < 8; ++t){
      int col = col0 + t * 16 + m;
      #pragma unroll
      for (int r = 0; r < 4; ++r){
        int rr = row0 + g * 16 + q * 4 + r;
        if (rr < N) OUT[(size_t)rr * 256 + col] = f2bf(acc[g][t][r]);
      }
    }
}

// ---------------- aggregation v6: max-free softmax ----------------------------
__global__ __launch_bounds__(256) void aggregate6(
    const u16* __restrict__ ft, const float* __restrict__ el4, const float* __restrict__ er4,
    const int* __restrict__ rowptr, const int4* __restrict__ csrp,
    const u16* __restrict__ residb, u16* __restrict__ outb,
    u16* __restrict__ hf, int do_hf, int N)
{
  __shared__ float sal[4][64][4];
  __shared__ int   sof[4][64];
  const int w = threadIdx.x >> 6, lane = threadIdx.x & 63;
  const int d = blockIdx.x * 4 + w;
  if (d >= N) return;
  const int beg = rowptr[d], deg = rowptr[d + 1] - beg;
  const int H = lane >> 5;            // edge-parity half
  const int c = lane & 31;            // col group: cols c*8 .. c*8+7
  const int hg = c >> 3;              // head of those cols
  float acc[8] = {0.f, 0.f, 0.f, 0.f, 0.f, 0.f, 0.f, 0.f};

  if (deg > 0){
    const float4 erd = ((const float4*)er4)[d];
    const int dc = min(deg, 64);
    // max-free: logits are O(1) for this model (al/ar scale 0.1); clamp guards
    float x0 = 0.f, x1 = 0.f, x2 = 0.f, x3 = 0.f; int sc = 0;
    float d0 = 0.f, d1 = 0.f, d2 = 0.f, d3 = 0.f;
    for (int j = lane; j < deg; j += 64){
      int s = csrp[beg + j].x;
      float4 ql = ((const float4*)el4)[s];
      float e0 = ql.x + erd.x; e0 = (e0 > 0.f) ? e0 : 0.2f * e0;
      float e1 = ql.y + erd.y; e1 = (e1 > 0.f) ? e1 : 0.2f * e1;
      float e2 = ql.z + erd.z; e2 = (e2 > 0.f) ? e2 : 0.2f * e2;
      float e3 = ql.w + erd.w; e3 = (e3 > 0.f) ? e3 : 0.2f * e3;
      float t0 = __expf(fminf(e0, 60.f)), t1 = __expf(fminf(e1, 60.f));
      float t2 = __expf(fminf(e2, 60.f)), t3 = __expf(fminf(e3, 60.f));
      if (j < 64){ x0 = t0; x1 = t1; x2 = t2; x3 = t3; sc = s; }
      d0 += t0; d1 += t1; d2 += t2; d3 += t3;
    }
    for (int mk = 1; mk < dc; mk <<= 1){
      d0 += __shfl_xor(d0, mk); d1 += __shfl_xor(d1, mk);
      d2 += __shfl_xor(d2, mk); d3 += __shfl_xor(d3, mk);
    }
    const float i0 = 1.f / d0, i1 = 1.f / d1, i2 = 1.f / d2, i3 = 1.f / d3;

    for (int c0 = 0; c0 < deg; c0 += 64){
      int cs = min(64, deg - c0);
      if (lane < cs){
        float t0, t1, t2, t3; int s;
        if (c0 == 0){ t0 = x0; t1 = x1; t2 = x2; t3 = x3; s = sc; }
        else {
          s = csrp[beg + c0 + lane].x;
          float4 ql = ((const float4*)el4)[s];
          float e0 = ql.x + erd.x; e0 = (e0 > 0.f) ? e0 : 0.2f * e0;
          float e1 = ql.y + erd.y; e1 = (e1 > 0.f) ? e1 : 0.2f * e1;
          float e2 = ql.z + erd.z; e2 = (e2 > 0.f) ? e2 : 0.2f * e2;
          float e3 = ql.w + erd.w; e3 = (e3 > 0.f) ? e3 : 0.2f * e3;
          t0 = __expf(fminf(e0, 60.f)); t1 = __expf(fminf(e1, 60.f));
          t2 = __expf(fminf(e2, 60.f)); t3 = __expf(fminf(e3, 60.f));
        }
        sal[w][lane][0] = t0 * i0; sal[w][lane][1] = t1 * i1;
        sal[w][lane][2] = t2 * i2; sal[w][lane][3] = t3 * i3;
        sof[w][lane] = s << 9;                      // s * 512 bytes
      }
      __builtin_amdgcn_wave_barrier();
      for (int j0 = 0; j0 < cs; j0 += 4){
        int jA = j0 + H, jB = j0 + 2 + H;
        bool bA = jA < cs, bB = jB < cs;
        float aA = 0.f, aB = 0.f;
        int offA = 0, offB = 0;
        if (bA){ aA = sal[w][jA][hg]; offA = sof[w][jA]; }
        if (bB){ aB = sal[w][jB][hg]; offB = sof[w][jB]; }
        uint4 vA = {}, vB = {};
        if (bA) vA = *(const uint4*)((const char*)ft + (size_t)(unsigned)offA + c * 16);
        if (bB) vB = *(const uint4*)((const char*)ft + (size_t)(unsigned)offB + c * 16);
        if (bA){
          fma2(acc[0], acc[1], vA.x, aA);
          fma2(acc[2], acc[3], vA.y, aA);
          fma2(acc[4], acc[5], vA.z, aA);
          fma2(acc[6], acc[7], vA.w, aA);
        }
        if (bB){
          fma2(acc[0], acc[1], vB.x, aB);
          fma2(acc[2], acc[3], vB.y, aB);
          fma2(acc[4], acc[5], vB.z, aB);
          fma2(acc[6], acc[7], vB.w, aB);
        }
      }
      __builtin_amdgcn_wave_barrier();
    }
  }
  // combine the two edge-parity halves
  #pragma unroll
  for (int i = 0; i < 8; ++i) acc[i] += __shfl_xor(acc[i], 32);
  uint4 rv = *(const uint4*)(residb + (size_t)d * 256 + c * 8);
  float rr[8];
  {
    union { unsigned u; float f; } t;
    t.u = rv.x << 16; rr[0] = t.f; t.u = rv.x & 0xffff0000u; rr[1] = t.f;
    t.u = rv.y << 16; rr[2] = t.f; t.u = rv.y & 0xffff0000u; rr[3] = t.f;
    t.u = rv.z << 16; rr[4] = t.f; t.u = rv.z & 0xffff0000u; rr[5] = t.f;
    t.u = rv.w << 16; rr[6] = t.f; t.u = rv.w & 0xffff0000u; rr[7] = t.f;
  }
  if (!do_hf){
    if (H == 0){
      float o[8];
      #pragma unroll
      for (int i = 0; i < 8; ++i) o[i] = fmaxf(acc[i] + rr[i], 0.f);
      uint4 ov;
      ov.x = pkbf(o[0], o[1]); ov.y = pkbf(o[2], o[3]);
      ov.z = pkbf(o[4], o[5]); ov.w = pkbf(o[6], o[7]);
      *(uint4*)(outb + (size_t)d * 256 + c * 8) = ov;
    }
  } else {
    #pragma unroll
    for (int i = 0; i < 8; ++i){
      float o = acc[i] + rr[i];
      o += __shfl_xor(o, 8);
      o += __shfl_xor(o, 16);
      acc[i] = 0.25f * o;
    }
    if (lane < 8){
      uint4 ov;
      ov.x = pkbf(acc[0], acc[1]); ov.y = pkbf(acc[2], acc[3]);
      ov.z = pkbf(acc[4], acc[5]); ov.w = pkbf(acc[6], acc[7]);
      *(uint4*)(hf + (size_t)d * 64 + lane * 8) = ov;
    }
  }
}

// ---------------- MFMA edge MLP, CSR-ordered ----------------------------------
__global__ __launch_bounds__(256) void edge_mlp_csr(
    const u16* __restrict__ hfb, const int4* __restrict__ csrp,
    const u16* __restrict__ Wm1, const u16* __restrict__ bm1,
    const u16* __restrict__ Wm2, const u16* __restrict__ bm2,
    void* __restrict__ out, int E, const int* __restrict__ flag)
{
  const int lane = threadIdx.x & 63;
  const int m = lane & 15;
  const int q = lane >> 4;
  const int is_f32 = *flag;

  bf16x8 bfr[4][2];
  #pragma unroll
  for (int t = 0; t < 4; ++t)
    #pragma unroll
    for (int ks = 0; ks < 2; ++ks)
      #pragma unroll
      for (int j = 0; j < 8; ++j)
        bfr[t][ks][j] = (short)Wm1[(size_t)(ks * 32 + q * 8 + j) * 64 + t * 16 + m];

  float b1v[4], w2v[4];
  #pragma unroll
  for (int t = 0; t < 4; ++t){
    b1v[t] = bf2f(bm1[t * 16 + m]);
    w2v[t] = bf2f(Wm2[t * 16 + m]);
  }
  const float b2 = bf2f(bm2[0]);

  const int wid = blockIdx.x * 4 + (threadIdx.x >> 6);
  const int nw  = gridDim.x * 4;
  for (int e0 = wid * 16; e0 < E; e0 += nw * 16){
    int e = e0 + m; if (e >= E) e = E - 1;
    int4 ed = csrp[e];
    const u16* ps = hfb + (size_t)ed.x * 64;
    const u16* pd = hfb + (size_t)ed.y * 64;
    union { bf16x8 v; uint4 u; } af[2];
    #pragma unroll
    for (int ks = 0; ks < 2; ++ks){
      bf16x8 vs = *(const bf16x8*)(ps + ks * 32 + q * 8);
      bf16x8 vd = *(const bf16x8*)(pd + ks * 32 + q * 8);
      unsigned pk[4];
      #pragma unroll
      for (int pp = 0; pp < 4; ++pp){
        float a0 = fabsf(bf2f((u16)vs[2 * pp])     - bf2f((u16)vd[2 * pp]));
        float a1 = fabsf(bf2f((u16)vs[2 * pp + 1]) - bf2f((u16)vd[2 * pp + 1]));
        pk[pp] = pkbf(a0, a1);
      }
      af[ks].u = make_uint4(pk[0], pk[1], pk[2], pk[3]);
    }
    f32x4 acc[4];
    #pragma unroll
    for (int t = 0; t < 4; ++t) acc[t] = (f32x4){0.f, 0.f, 0.f, 0.f};
    #pragma unroll
    for (int ks = 0; ks < 2; ++ks)
      #pragma unroll
      for (int t = 0; t < 4; ++t)
        acc[t] = __builtin_amdgcn_mfma_f32_16x16x32_bf16(af[ks].v, bfr[t][ks], acc[t], 0, 0, 0);
    #pragma unroll
    for (int r = 0; r < 4; ++r){
      float p = 0.f;
      #pragma unroll
      for (int t = 0; t < 4; ++t)
        p += fmaxf(acc[t][r] + b1v[t], 0.f) * w2v[t];
      #pragma unroll
      for (int mm = 1; mm < 16; mm <<= 1) p += __shfl_xor(p, mm);
      int slot = e0 + q * 4 + r;
      if (m == 0 && slot < E){
        int eid = csrp[slot].z;
        float sc = 1.f / (1.f + __expf(-(p + b2)));
        if (is_f32) ((float*)out)[eid] = sc;
        else        ((u16*)out)[eid]   = f2bf(sc);
      }
    }
  }
}

extern "C" void kernel_launch(void* const* d_in, const int* in_sizes, int n_in,
                              void* d_out, int out_size, void* d_ws, size_t ws_size,
                              hipStream_t stream)
{
  const int* src = (const int*)d_in[1];
  const int* dst = (const int*)d_in[2];

  const int N = in_sizes[0] / 128;
  const int E = in_sizes[1];

  char* p = (char*)d_ws;
  auto alloc = [&](size_t bytes) -> char* {
    char* r = p; p += (bytes + 255) & ~(size_t)255; return r;
  };
  int* flag   = (int*)  alloc(4);
  u16* hc     = (u16*)  alloc((size_t)N * 128 * 2);
  u16* FT     = (u16*)  alloc((size_t)N * 256 * 2);
  u16* XA     = (u16*)  alloc((size_t)N * 256 * 2);
  u16* XB     = (u16*)  alloc((size_t)N * 256 * 2);
  float* el   = (float*)alloc((size_t)N * 4 * 4);
  float* er   = (float*)alloc((size_t)N * 4 * 4);
  u16* hfb    = (u16*)  alloc((size_t)N * 64 * 2);
  int* rowptr = (int*)  alloc((size_t)(N + 1) * 4);
  int* cursor = (int*)  alloc((size_t)N * 4);
  int4* csrp  = (int4*) alloc((size_t)E * 16);
  int* bsums  = (int*)  alloc(1024);
  u16* WT1    = (u16*)  alloc(128 * 256 * 2);
  u16* WTr1   = (u16*)  alloc(128 * 256 * 2);
  u16* WT2    = (u16*)  alloc(256 * 256 * 2);
  u16* WT3    = (u16*)  alloc(256 * 256 * 2);
  u16* al1c   = (u16*)  alloc(256 * 2);
  u16* ar1c   = (u16*)  alloc(256 * 2);
  u16* al2c   = (u16*)  alloc(256 * 2);
  u16* ar2c   = (u16*)  alloc(256 * 2);
  u16* al3c   = (u16*)  alloc(256 * 2);
  u16* ar3c   = (u16*)  alloc(256 * 2);
  u16* Wm1c   = (u16*)  alloc(4096 * 2);
  u16* bm1c   = (u16*)  alloc(64 * 2);
  u16* Wm2c   = (u16*)  alloc(64 * 2);
  u16* bm2c   = (u16*)  alloc(2);

  const int nb = (N + 255) / 256;
  const int ge = (E + 255) / 256;

  // dtype sniff + canonicalize
  k_sniff<<<1, 256, 0, stream>>>((const u16*)d_in[0], flag);
  k_canon4<<<(N * 32 + 255) / 256, 256, 0, stream>>>(d_in[0], hc, N * 32, flag);
  {
    Canon10 c;
    c.e[0] = {d_in[5],  al1c, 256};  c.e[1] = {d_in[6],  ar1c, 256};
    c.e[2] = {d_in[8],  al2c, 256};  c.e[3] = {d_in[9],  ar2c, 256};
    c.e[4] = {d_in[11], al3c, 256};  c.e[5] = {d_in[12], ar3c, 256};
    c.e[6] = {d_in[13], Wm1c, 4096}; c.e[7] = {d_in[14], bm1c, 64};
    c.e[8] = {d_in[15], Wm2c, 64};   c.e[9] = {d_in[16], bm2c, 1};
    dim3 g((4096 + 255) / 256, 10);
    k_canon10<<<g, 256, 0, stream>>>(c, flag);
  }
  {
    CanonW4 c;
    c.e[0] = {d_in[3],  WT1,  128};  c.e[1] = {d_in[4],  WTr1, 128};
    c.e[2] = {d_in[7],  WT2,  256};  c.e[3] = {d_in[10], WT3,  256};
    dim3 g(256, 4);
    k_canonw<<<g, 256, 0, stream>>>(c, flag);
  }

  // CSR by dst
  hipMemsetAsync(cursor, 0, (size_t)N * 4, stream);
  k_hist<<<ge, 256, 0, stream>>>(dst, cursor, E);
  k_scan1<<<nb, 256, 0, stream>>>(cursor, rowptr, bsums, N);
  k_scan2<<<1, 256, 0, stream>>>(bsums, nb);
  k_scan3<<<nb, 256, 0, stream>>>(rowptr, bsums, cursor, N);
  k_scatter<<<ge, 256, 0, stream>>>(src, dst, cursor, csrp, E);

  const dim3 gA3((N + 127) / 128, 2);
  const int gG = (N + 3) / 4;
  // layer 1
  mfma_gemm_attn3<<<gA3, 256, 0, stream>>>(hc, WT1, FT, al1c, ar1c, el, er, N, 128);
  mfma_gemm3<<<gA3, 256, 0, stream>>>(hc, WTr1, XA, N, 128);
  aggregate6<<<gG, 256, 0, stream>>>(FT, el, er, rowptr, csrp, XA, XB, nullptr, 0, N);
  // layer 2
  mfma_gemm_attn3<<<gA3, 256, 0, stream>>>(XB, WT2, FT, al2c, ar2c, el, er, N, 256);
  aggregate6<<<gG, 256, 0, stream>>>(FT, el, er, rowptr, csrp, XB, XA, nullptr, 0, N);
  // layer 3 (fused head-mean -> hf bf16)
  mfma_gemm_attn3<<<gA3, 256, 0, stream>>>(XA, WT3, FT, al3c, ar3c, el, er, N, 256);
  aggregate6<<<gG, 256, 0, stream>>>(FT, el, er, rowptr, csrp, XA, nullptr, hfb, 1, N);
  // edge MLP (MFMA, CSR-ordered for dst-row locality)
  edge_mlp_csr<<<2048, 256, 0, stream>>>(hfb, csrp, Wm1c, bm1c, Wm2c, bm2c,
                                         d_out, E, flag);
}

// Round 10
// 525.319 us; speedup vs baseline: 1.3015x; 1.1460x over previous
//
#include <hip/hip_runtime.h>
#include <hip/hip_bf16.h>

typedef unsigned short u16;
typedef unsigned char u8;
typedef __attribute__((ext_vector_type(8))) short bf16x8;
typedef __attribute__((ext_vector_type(4))) float f32x4;
typedef __attribute__((ext_vector_type(2))) float f32x2;

__device__ __forceinline__ float bf2f(u16 u){
  union { unsigned int i; float f; } v; v.i = ((unsigned int)u) << 16; return v.f;
}
__device__ __forceinline__ u16 f2bf(float f){
  union { float f; unsigned int i; } v; v.f = f;
  unsigned int lsb = (v.i >> 16) & 1u;
  v.i += 0x7fffu + lsb;
  return (u16)(v.i >> 16);
}
__device__ __forceinline__ unsigned pkbf(float a, float b){
  __hip_bfloat162 h = __float22bfloat162_rn(make_float2(a, b));
  union { __hip_bfloat162 h2; unsigned u; } c; c.h2 = h; return c.u;
}
__device__ __forceinline__ u8 f2fp8(float f){
  int p = __builtin_amdgcn_cvt_pk_fp8_f32(f, f, 0, false);
  return (u8)(p & 0xFF);
}

// ---------------- dtype sniffer ----------------
__global__ void k_sniff(const u16* __restrict__ p, int* __restrict__ flag){
  __shared__ int s[256];
  int tid = threadIdx.x;
  u16 v = p[2 * tid];
  int e = (v >> 7) & 0xFF;
  s[tid] = (e >= 100 && e <= 135) ? 1 : 0;
  __syncthreads();
  for (int off = 128; off; off >>= 1){
    if (tid < off) s[tid] += s[tid + off];
    __syncthreads();
  }
  if (tid == 0) *flag = (s[0] < 180) ? 1 : 0;
}
__global__ void k_canon4(const void* __restrict__ src, u16* __restrict__ dst,
                         int n4, const int* __restrict__ flag){
  int i = blockIdx.x * 256 + threadIdx.x;
  if (i < n4){
    u16 o[4];
    if (*flag){
      float4 v = ((const float4*)src)[i];
      o[0] = f2bf(v.x); o[1] = f2bf(v.y); o[2] = f2bf(v.z); o[3] = f2bf(v.w);
    } else {
      uint2 v = ((const uint2*)src)[i];
      o[0] = (u16)v.x; o[1] = (u16)(v.x >> 16); o[2] = (u16)v.y; o[3] = (u16)(v.y >> 16);
    }
    uint2 w; w.x = o[0] | ((unsigned)o[1] << 16); w.y = o[2] | ((unsigned)o[3] << 16);
    ((uint2*)dst)[i] = w;
  }
}
struct CanonEnt { const void* s; u16* d; int n; };
struct Canon10 { CanonEnt e[10]; };
__global__ void k_canon10(Canon10 c, const int* __restrict__ flag){
  CanonEnt en = c.e[blockIdx.y];
  int i = blockIdx.x * 256 + threadIdx.x;
  if (i < en.n){
    if (*flag) en.d[i] = f2bf(((const float*)en.s)[i]);
    else       en.d[i] = ((const u16*)en.s)[i];
  }
}
struct CanonWEnt { const void* s; u16* wt; int K; };
struct CanonW4 { CanonWEnt e[4]; };
__global__ void k_canonw(CanonW4 c, const int* __restrict__ flag){
  CanonWEnt en = c.e[blockIdx.y];
  int i = blockIdx.x * 256 + threadIdx.x;
  if (i < 256 * en.K){
    int k = i >> 8, cc = i & 255;
    u16 b;
    if (*flag) b = f2bf(((const float*)en.s)[i]);
    else       b = ((const u16*)en.s)[i];
    en.wt[(size_t)cc * en.K + k] = b;
  }
}

// ---------------- CSR build ----------------
__global__ void k_hist(const int* __restrict__ dst, int* __restrict__ cnt, int E){
  int i = blockIdx.x * 256 + threadIdx.x;
  if (i < E) atomicAdd(&cnt[dst[i]], 1);
}
__global__ void k_scan1(const int* __restrict__ cnt, int* __restrict__ rowptr,
                        int* __restrict__ bsums, int N){
  __shared__ int s[256];
  int i = blockIdx.x * 256 + threadIdx.x;
  int v = (i < N) ? cnt[i] : 0;
  s[threadIdx.x] = v; __syncthreads();
  for (int off = 1; off < 256; off <<= 1){
    int x = 0;
    if (threadIdx.x >= off) x = s[threadIdx.x - off];
    __syncthreads();
    s[threadIdx.x] += x;
    __syncthreads();
  }
  if (i < N) rowptr[i + 1] = s[threadIdx.x];
  if (threadIdx.x == 255) bsums[blockIdx.x] = s[255];
}
__global__ void k_scan2(int* __restrict__ bsums, int nb){
  __shared__ int s[256];
  int t = threadIdx.x;
  int v = (t < nb) ? bsums[t] : 0;
  s[t] = v; __syncthreads();
  for (int off = 1; off < 256; off <<= 1){
    int x = 0;
    if (t >= off) x = s[t - off];
    __syncthreads();
    s[t] += x;
    __syncthreads();
  }
  if (t < nb) bsums[t] = s[t] - v;                // exclusive
}
__global__ void k_scan3(int* __restrict__ rowptr, const int* __restrict__ bsums,
                        int* __restrict__ cursor, int N){
  int i = blockIdx.x * 256 + threadIdx.x;
  if (i < N){
    int v = rowptr[i + 1] + bsums[blockIdx.x];
    rowptr[i + 1] = v;
    if (i + 1 < N) cursor[i + 1] = v;
    if (i == 0){ rowptr[0] = 0; cursor[0] = 0; }
  }
}
// 4 independent atomic->store chains per thread to overlap atomic latency
__global__ void k_scatter(const int* __restrict__ src, const int* __restrict__ dst,
                          int* __restrict__ cursor, int4* __restrict__ csrp, int E){
  const int T = gridDim.x * 256;
  const int tid = blockIdx.x * 256 + threadIdx.x;
  int e0 = tid, e1 = tid + T, e2 = tid + 2 * T, e3 = tid + 3 * T;
  int s0 = 0, s1 = 0, s2 = 0, s3 = 0, d0 = 0, d1 = 0, d2 = 0, d3 = 0;
  if (e0 < E){ s0 = src[e0]; d0 = dst[e0]; }
  if (e1 < E){ s1 = src[e1]; d1 = dst[e1]; }
  if (e2 < E){ s2 = src[e2]; d2 = dst[e2]; }
  if (e3 < E){ s3 = src[e3]; d3 = dst[e3]; }
  int p0 = 0, p1 = 0, p2 = 0, p3 = 0;
  if (e0 < E) p0 = atomicAdd(&cursor[d0], 1);
  if (e1 < E) p1 = atomicAdd(&cursor[d1], 1);
  if (e2 < E) p2 = atomicAdd(&cursor[d2], 1);
  if (e3 < E) p3 = atomicAdd(&cursor[d3], 1);
  if (e0 < E) csrp[p0] = make_int4(s0, d0, e0, 0);
  if (e1 < E) csrp[p1] = make_int4(s1, d1, e1, 0);
  if (e2 < E) csrp[p2] = make_int4(s2, d2, e2, 0);
  if (e3 < E) csrp[p3] = make_int4(s3, d3, e3, 0);
}

// ---------------- MFMA node GEMM v3: column-split x2 (bf16 out) ---------------
__global__ __launch_bounds__(256, 4) void mfma_gemm3(
    const u16* __restrict__ X, const u16* __restrict__ WT,
    u16* __restrict__ OUT, int N, int K)
{
  const int wave = threadIdx.x >> 6;
  const int lane = threadIdx.x & 63;
  const int m = lane & 15;
  const int q = lane >> 4;
  const int row0 = blockIdx.x * 128 + wave * 32;
  const int col0 = blockIdx.y * 128;
  f32x4 acc[2][8];
  #pragma unroll
  for (int g = 0; g < 2; ++g)
    #pragma unroll
    for (int t = 0; t < 8; ++t) acc[g][t] = (f32x4){0.f, 0.f, 0.f, 0.f};
  const int rA = row0 + m, rB = row0 + 16 + m;
  const bool vA = rA < N, vB = rB < N;
  const u16* apA = X + (size_t)rA * K + q * 8;
  const u16* apB = X + (size_t)rB * K + q * 8;
  for (int k0 = 0; k0 < K; k0 += 32){
    bf16x8 aA = {}, aB = {};
    if (vA) aA = *(const bf16x8*)(apA + k0);
    if (vB) aB = *(const bf16x8*)(apB + k0);
    #pragma unroll
    for (int t = 0; t < 8; ++t){
      const u16* bptr = WT + (size_t)(col0 + t * 16 + m) * K + k0 + q * 8;
      bf16x8 b = *(const bf16x8*)bptr;
      acc[0][t] = __builtin_amdgcn_mfma_f32_16x16x32_bf16(aA, b, acc[0][t], 0, 0, 0);
      acc[1][t] = __builtin_amdgcn_mfma_f32_16x16x32_bf16(aB, b, acc[1][t], 0, 0, 0);
    }
  }
  #pragma unroll
  for (int g = 0; g < 2; ++g)
    #pragma unroll
    for (int t = 0; t < 8; ++t){
      int col = col0 + t * 16 + m;
      #pragma unroll
      for (int r = 0; r < 4; ++r){
        int rr = row0 + g * 16 + q * 4 + r;
        if (rr < N) OUT[(size_t)rr * 256 + col] = f2bf(acc[g][t][r]);
      }
    }
}

// ---------------- GEMM v3 + fused attention logits, fp8 FT out ----------------
__global__ __launch_bounds__(256, 4) void mfma_gemm_attn3(
    const u16* __restrict__ X, const u16* __restrict__ WT,
    u8* __restrict__ OUT8, const u16* __restrict__ al, const u16* __restrict__ ar,
    float* __restrict__ el4, float* __restrict__ er4, int N, int K)
{
  const int wave = threadIdx.x >> 6;
  const int lane = threadIdx.x & 63;
  const int m = lane & 15;
  const int q = lane >> 4;
  const int row0 = blockIdx.x * 128 + wave * 32;
  const int col0 = blockIdx.y * 128;
  f32x4 acc[2][8];
  #pragma unroll
  for (int g = 0; g < 2; ++g)
    #pragma unroll
    for (int t = 0; t < 8; ++t) acc[g][t] = (f32x4){0.f, 0.f, 0.f, 0.f};
  const int rA = row0 + m, rB = row0 + 16 + m;
  const bool vA = rA < N, vB = rB < N;
  const u16* apA = X + (size_t)rA * K + q * 8;
  const u16* apB = X + (size_t)rB * K + q * 8;
  for (int k0 = 0; k0 < K; k0 += 32){
    bf16x8 aA = {}, aB = {};
    if (vA) aA = *(const bf16x8*)(apA + k0);
    if (vB) aB = *(const bf16x8*)(apB + k0);
    #pragma unroll
    for (int t = 0; t < 8; ++t){
      const u16* bptr = WT + (size_t)(col0 + t * 16 + m) * K + k0 + q * 8;
      bf16x8 b = *(const bf16x8*)bptr;
      acc[0][t] = __builtin_amdgcn_mfma_f32_16x16x32_bf16(aA, b, acc[0][t], 0, 0, 0);
      acc[1][t] = __builtin_amdgcn_mfma_f32_16x16x32_bf16(aB, b, acc[1][t], 0, 0, 0);
    }
  }
  // attn vectors for this block's 2 heads (cols col0..col0+127)
  float alv[8], arv[8];
  #pragma unroll
  for (int t = 0; t < 8; ++t){
    alv[t] = bf2f(al[col0 + t * 16 + m]);
    arv[t] = bf2f(ar[col0 + t * 16 + m]);
  }
  #pragma unroll
  for (int g = 0; g < 2; ++g)
    #pragma unroll
    for (int r = 0; r < 4; ++r){
      float pe[2] = {0.f, 0.f}, pr[2] = {0.f, 0.f};
      #pragma unroll
      for (int t = 0; t < 8; ++t){
        pe[t >> 2] += acc[g][t][r] * alv[t];
        pr[t >> 2] += acc[g][t][r] * arv[t];
      }
      #pragma unroll
      for (int mk = 1; mk < 16; mk <<= 1){
        pe[0] += __shfl_xor(pe[0], mk); pe[1] += __shfl_xor(pe[1], mk);
        pr[0] += __shfl_xor(pr[0], mk); pr[1] += __shfl_xor(pr[1], mk);
      }
      int rr = row0 + g * 16 + q * 4 + r;
      if (m == 0 && rr < N){
        *(float2*)(el4 + (size_t)rr * 4 + blockIdx.y * 2) = make_float2(pe[0], pe[1]);
        *(float2*)(er4 + (size_t)rr * 4 + blockIdx.y * 2) = make_float2(pr[0], pr[1]);
      }
    }
  #pragma unroll
  for (int g = 0; g < 2; ++g)
    #pragma unroll
    for (int t = 0; t < 8; ++t){
      int col = col0 + t * 16 + m;
      #pragma unroll
      for (int r = 0; r < 4; ++r){
        int rr = row0 + g * 16 + q * 4 + r;
        if (rr < N) OUT8[(size_t)rr * 256 + col] = f2fp8(acc[g][t][r]);
      }
    }
}

// ---------------- aggregation v7: fp8 ft gather, max-free softmax -------------
__global__ __launch_bounds__(256) void aggregate7(
    const u8* __restrict__ ft8, const float* __restrict__ el4, const float* __restrict__ er4,
    const int* __restrict__ rowptr, const int4* __restrict__ csrp,
    const u16* __restrict__ residb, u16* __restrict__ outb,
    u16* __restrict__ hf, int do_hf, int N)
{
  __shared__ float sal[4][64][4];
  __shared__ int   sof[4][64];
  const int w = threadIdx.x >> 6, lane = threadIdx.x & 63;
  const int d = blockIdx.x * 4 + w;
  if (d >= N) return;
  const int beg = rowptr[d], deg = rowptr[d + 1] - beg;
  const int H = lane >> 5;            // edge-parity half
  const int c = lane & 31;            // col group: cols c*8 .. c*8+7
  const int hg = c >> 3;              // head of those cols
  float acc[8] = {0.f, 0.f, 0.f, 0.f, 0.f, 0.f, 0.f, 0.f};

  if (deg > 0){
    const float4 erd = ((const float4*)er4)[d];
    const int dc = min(deg, 64);
    float x0 = 0.f, x1 = 0.f, x2 = 0.f, x3 = 0.f; int sc = 0;
    float d0 = 0.f, d1 = 0.f, d2 = 0.f, d3 = 0.f;
    for (int j = lane; j < deg; j += 64){
      int s = csrp[beg + j].x;
      float4 ql = ((const float4*)el4)[s];
      float e0 = ql.x + erd.x; e0 = (e0 > 0.f) ? e0 : 0.2f * e0;
      float e1 = ql.y + erd.y; e1 = (e1 > 0.f) ? e1 : 0.2f * e1;
      float e2 = ql.z + erd.z; e2 = (e2 > 0.f) ? e2 : 0.2f * e2;
      float e3 = ql.w + erd.w; e3 = (e3 > 0.f) ? e3 : 0.2f * e3;
      float t0 = __expf(fminf(e0, 60.f)), t1 = __expf(fminf(e1, 60.f));
      float t2 = __expf(fminf(e2, 60.f)), t3 = __expf(fminf(e3, 60.f));
      if (j < 64){ x0 = t0; x1 = t1; x2 = t2; x3 = t3; sc = s; }
      d0 += t0; d1 += t1; d2 += t2; d3 += t3;
    }
    for (int mk = 1; mk < dc; mk <<= 1){
      d0 += __shfl_xor(d0, mk); d1 += __shfl_xor(d1, mk);
      d2 += __shfl_xor(d2, mk); d3 += __shfl_xor(d3, mk);
    }
    const float i0 = 1.f / d0, i1 = 1.f / d1, i2 = 1.f / d2, i3 = 1.f / d3;

    for (int c0 = 0; c0 < deg; c0 += 64){
      int cs = min(64, deg - c0);
      if (lane < cs){
        float t0, t1, t2, t3; int s;
        if (c0 == 0){ t0 = x0; t1 = x1; t2 = x2; t3 = x3; s = sc; }
        else {
          s = csrp[beg + c0 + lane].x;
          float4 ql = ((const float4*)el4)[s];
          float e0 = ql.x + erd.x; e0 = (e0 > 0.f) ? e0 : 0.2f * e0;
          float e1 = ql.y + erd.y; e1 = (e1 > 0.f) ? e1 : 0.2f * e1;
          float e2 = ql.z + erd.z; e2 = (e2 > 0.f) ? e2 : 0.2f * e2;
          float e3 = ql.w + erd.w; e3 = (e3 > 0.f) ? e3 : 0.2f * e3;
          t0 = __expf(fminf(e0, 60.f)); t1 = __expf(fminf(e1, 60.f));
          t2 = __expf(fminf(e2, 60.f)); t3 = __expf(fminf(e3, 60.f));
        }
        sal[w][lane][0] = t0 * i0; sal[w][lane][1] = t1 * i1;
        sal[w][lane][2] = t2 * i2; sal[w][lane][3] = t3 * i3;
        sof[w][lane] = s << 8;                      // s * 256 bytes (fp8 row)
      }
      __builtin_amdgcn_wave_barrier();
      for (int j0 = 0; j0 < cs; j0 += 4){
        int jA = j0 + H, jB = j0 + 2 + H;
        bool bA = jA < cs, bB = jB < cs;
        float aA = 0.f, aB = 0.f;
        int offA = 0, offB = 0;
        if (bA){ aA = sal[w][jA][hg]; offA = sof[w][jA]; }
        if (bB){ aB = sal[w][jB][hg]; offB = sof[w][jB]; }
        uint2 vA = {}, vB = {};
        if (bA) vA = *(const uint2*)(ft8 + (size_t)(unsigned)offA + c * 8);
        if (bB) vB = *(const uint2*)(ft8 + (size_t)(unsigned)offB + c * 8);
        if (bA){
          f32x2 u;
          u = __builtin_amdgcn_cvt_pk_f32_fp8(vA.x, 0); acc[0] += aA * u.x; acc[1] += aA * u.y;
          u = __builtin_amdgcn_cvt_pk_f32_fp8(vA.x, 1); acc[2] += aA * u.x; acc[3] += aA * u.y;
          u = __builtin_amdgcn_cvt_pk_f32_fp8(vA.y, 0); acc[4] += aA * u.x; acc[5] += aA * u.y;
          u = __builtin_amdgcn_cvt_pk_f32_fp8(vA.y, 1); acc[6] += aA * u.x; acc[7] += aA * u.y;
        }
        if (bB){
          f32x2 u;
          u = __builtin_amdgcn_cvt_pk_f32_fp8(vB.x, 0); acc[0] += aB * u.x; acc[1] += aB * u.y;
          u = __builtin_amdgcn_cvt_pk_f32_fp8(vB.x, 1); acc[2] += aB * u.x; acc[3] += aB * u.y;
          u = __builtin_amdgcn_cvt_pk_f32_fp8(vB.y, 0); acc[4] += aB * u.x; acc[5] += aB * u.y;
          u = __builtin_amdgcn_cvt_pk_f32_fp8(vB.y, 1); acc[6] += aB * u.x; acc[7] += aB * u.y;
        }
      }
      __builtin_amdgcn_wave_barrier();
    }
  }
  // combine the two edge-parity halves
  #pragma unroll
  for (int i = 0; i < 8; ++i) acc[i] += __shfl_xor(acc[i], 32);
  uint4 rv = *(const uint4*)(residb + (size_t)d * 256 + c * 8);
  float rr[8];
  {
    union { unsigned u; float f; } t;
    t.u = rv.x << 16; rr[0] = t.f; t.u = rv.x & 0xffff0000u; rr[1] = t.f;
    t.u = rv.y << 16; rr[2] = t.f; t.u = rv.y & 0xffff0000u; rr[3] = t.f;
    t.u = rv.z << 16; rr[4] = t.f; t.u = rv.z & 0xffff0000u; rr[5] = t.f;
    t.u = rv.w << 16; rr[6] = t.f; t.u = rv.w & 0xffff0000u; rr[7] = t.f;
  }
  if (!do_hf){
    if (H == 0){
      float o[8];
      #pragma unroll
      for (int i = 0; i < 8; ++i) o[i] = fmaxf(acc[i] + rr[i], 0.f);
      uint4 ov;
      ov.x = pkbf(o[0], o[1]); ov.y = pkbf(o[2], o[3]);
      ov.z = pkbf(o[4], o[5]); ov.w = pkbf(o[6], o[7]);
      *(uint4*)(outb + (size_t)d * 256 + c * 8) = ov;
    }
  } else {
    #pragma unroll
    for (int i = 0; i < 8; ++i){
      float o = acc[i] + rr[i];
      o += __shfl_xor(o, 8);
      o += __shfl_xor(o, 16);
      acc[i] = 0.25f * o;
    }
    if (lane < 8){
      uint4 ov;
      ov.x = pkbf(acc[0], acc[1]); ov.y = pkbf(acc[2], acc[3]);
      ov.z = pkbf(acc[4], acc[5]); ov.w = pkbf(acc[6], acc[7]);
      *(uint4*)(hf + (size_t)d * 64 + lane * 8) = ov;
    }
  }
}

// ---------------- MFMA edge MLP, CSR-ordered ----------------------------------
__global__ __launch_bounds__(256) void edge_mlp_csr(
    const u16* __restrict__ hfb, const int4* __restrict__ csrp,
    const u16* __restrict__ Wm1, const u16* __restrict__ bm1,
    const u16* __restrict__ Wm2, const u16* __restrict__ bm2,
    void* __restrict__ out, int E, const int* __restrict__ flag)
{
  const int lane = threadIdx.x & 63;
  const int m = lane & 15;
  const int q = lane >> 4;
  const int is_f32 = *flag;

  bf16x8 bfr[4][2];
  #pragma unroll
  for (int t = 0; t < 4; ++t)
    #pragma unroll
    for (int ks = 0; ks < 2; ++ks)
      #pragma unroll
      for (int j = 0; j < 8; ++j)
        bfr[t][ks][j] = (short)Wm1[(size_t)(ks * 32 + q * 8 + j) * 64 + t * 16 + m];

  float b1v[4], w2v[4];
  #pragma unroll
  for (int t = 0; t < 4; ++t){
    b1v[t] = bf2f(bm1[t * 16 + m]);
    w2v[t] = bf2f(Wm2[t * 16 + m]);
  }
  const float b2 = bf2f(bm2[0]);

  const int wid = blockIdx.x * 4 + (threadIdx.x >> 6);
  const int nw  = gridDim.x * 4;
  for (int e0 = wid * 16; e0 < E; e0 += nw * 16){
    int e = e0 + m; if (e >= E) e = E - 1;
    int4 ed = csrp[e];
    const u16* ps = hfb + (size_t)ed.x * 64;
    const u16* pd = hfb + (size_t)ed.y * 64;
    union { bf16x8 v; uint4 u; } af[2];
    #pragma unroll
    for (int ks = 0; ks < 2; ++ks){
      bf16x8 vs = *(const bf16x8*)(ps + ks * 32 + q * 8);
      bf16x8 vd = *(const bf16x8*)(pd + ks * 32 + q * 8);
      unsigned pk[4];
      #pragma unroll
      for (int pp = 0; pp < 4; ++pp){
        float a0 = fabsf(bf2f((u16)vs[2 * pp])     - bf2f((u16)vd[2 * pp]));
        float a1 = fabsf(bf2f((u16)vs[2 * pp + 1]) - bf2f((u16)vd[2 * pp + 1]));
        pk[pp] = pkbf(a0, a1);
      }
      af[ks].u = make_uint4(pk[0], pk[1], pk[2], pk[3]);
    }
    f32x4 acc[4];
    #pragma unroll
    for (int t = 0; t < 4; ++t) acc[t] = (f32x4){0.f, 0.f, 0.f, 0.f};
    #pragma unroll
    for (int ks = 0; ks < 2; ++ks)
      #pragma unroll
      for (int t = 0; t < 4; ++t)
        acc[t] = __builtin_amdgcn_mfma_f32_16x16x32_bf16(af[ks].v, bfr[t][ks], acc[t], 0, 0, 0);
    #pragma unroll
    for (int r = 0; r < 4; ++r){
      float p = 0.f;
      #pragma unroll
      for (int t = 0; t < 4; ++t)
        p += fmaxf(acc[t][r] + b1v[t], 0.f) * w2v[t];
      #pragma unroll
      for (int mm = 1; mm < 16; mm <<= 1) p += __shfl_xor(p, mm);
      int slot = e0 + q * 4 + r;
      if (m == 0 && slot < E){
        int eid = csrp[slot].z;
        float sc = 1.f / (1.f + __expf(-(p + b2)));
        if (is_f32) ((float*)out)[eid] = sc;
        else        ((u16*)out)[eid]   = f2bf(sc);
      }
    }
  }
}

extern "C" void kernel_launch(void* const* d_in, const int* in_sizes, int n_in,
                              void* d_out, int out_size, void* d_ws, size_t ws_size,
                              hipStream_t stream)
{
  const int* src = (const int*)d_in[1];
  const int* dst = (const int*)d_in[2];

  const int N = in_sizes[0] / 128;
  const int E = in_sizes[1];

  char* p = (char*)d_ws;
  auto alloc = [&](size_t bytes) -> char* {
    char* r = p; p += (bytes + 255) & ~(size_t)255; return r;
  };
  int* flag   = (int*)  alloc(4);
  u16* hc     = (u16*)  alloc((size_t)N * 128 * 2);
  u8*  FT8    = (u8*)   alloc((size_t)N * 256);
  u16* XA     = (u16*)  alloc((size_t)N * 256 * 2);
  u16* XB     = (u16*)  alloc((size_t)N * 256 * 2);
  float* el   = (float*)alloc((size_t)N * 4 * 4);
  float* er   = (float*)alloc((size_t)N * 4 * 4);
  u16* hfb    = (u16*)  alloc((size_t)N * 64 * 2);
  int* rowptr = (int*)  alloc((size_t)(N + 1) * 4);
  int* cursor = (int*)  alloc((size_t)N * 4);
  int4* csrp  = (int4*) alloc((size_t)E * 16);
  int* bsums  = (int*)  alloc(1024);
  u16* WT1    = (u16*)  alloc(128 * 256 * 2);
  u16* WTr1   = (u16*)  alloc(128 * 256 * 2);
  u16* WT2    = (u16*)  alloc(256 * 256 * 2);
  u16* WT3    = (u16*)  alloc(256 * 256 * 2);
  u16* al1c   = (u16*)  alloc(256 * 2);
  u16* ar1c   = (u16*)  alloc(256 * 2);
  u16* al2c   = (u16*)  alloc(256 * 2);
  u16* ar2c   = (u16*)  alloc(256 * 2);
  u16* al3c   = (u16*)  alloc(256 * 2);
  u16* ar3c   = (u16*)  alloc(256 * 2);
  u16* Wm1c   = (u16*)  alloc(4096 * 2);
  u16* bm1c   = (u16*)  alloc(64 * 2);
  u16* Wm2c   = (u16*)  alloc(64 * 2);
  u16* bm2c   = (u16*)  alloc(2);

  const int nb = (N + 255) / 256;
  const int ge = (E + 255) / 256;

  // dtype sniff + canonicalize
  k_sniff<<<1, 256, 0, stream>>>((const u16*)d_in[0], flag);
  k_canon4<<<(N * 32 + 255) / 256, 256, 0, stream>>>(d_in[0], hc, N * 32, flag);
  {
    Canon10 c;
    c.e[0] = {d_in[5],  al1c, 256};  c.e[1] = {d_in[6],  ar1c, 256};
    c.e[2] = {d_in[8],  al2c, 256};  c.e[3] = {d_in[9],  ar2c, 256};
    c.e[4] = {d_in[11], al3c, 256};  c.e[5] = {d_in[12], ar3c, 256};
    c.e[6] = {d_in[13], Wm1c, 4096}; c.e[7] = {d_in[14], bm1c, 64};
    c.e[8] = {d_in[15], Wm2c, 64};   c.e[9] = {d_in[16], bm2c, 1};
    dim3 g((4096 + 255) / 256, 10);
    k_canon10<<<g, 256, 0, stream>>>(c, flag);
  }
  {
    CanonW4 c;
    c.e[0] = {d_in[3],  WT1,  128};  c.e[1] = {d_in[4],  WTr1, 128};
    c.e[2] = {d_in[7],  WT2,  256};  c.e[3] = {d_in[10], WT3,  256};
    dim3 g(256, 4);
    k_canonw<<<g, 256, 0, stream>>>(c, flag);
  }

  // CSR by dst
  hipMemsetAsync(cursor, 0, (size_t)N * 4, stream);
  k_hist<<<ge, 256, 0, stream>>>(dst, cursor, E);
  k_scan1<<<nb, 256, 0, stream>>>(cursor, rowptr, bsums, N);
  k_scan2<<<1, 256, 0, stream>>>(bsums, nb);
  k_scan3<<<nb, 256, 0, stream>>>(rowptr, bsums, cursor, N);
  k_scatter<<<(E + 1023) / 1024, 256, 0, stream>>>(src, dst, cursor, csrp, E);

  const dim3 gA3((N + 127) / 128, 2);
  const int gG = (N + 3) / 4;
  // layer 1
  mfma_gemm_attn3<<<gA3, 256, 0, stream>>>(hc, WT1, FT8, al1c, ar1c, el, er, N, 128);
  mfma_gemm3<<<gA3, 256, 0, stream>>>(hc, WTr1, XA, N, 128);
  aggregate7<<<gG, 256, 0, stream>>>(FT8, el, er, rowptr, csrp, XA, XB, nullptr, 0, N);
  // layer 2
  mfma_gemm_attn3<<<gA3, 256, 0, stream>>>(XB, WT2, FT8, al2c, ar2c, el, er, N, 256);
  aggregate7<<<gG, 256, 0, stream>>>(FT8, el, er, rowptr, csrp, XB, XA, nullptr, 0, N);
  // layer 3 (fused head-mean -> hf bf16)
  mfma_gemm_attn3<<<gA3, 256, 0, stream>>>(XA, WT3, FT8, al3c, ar3c, el, er, N, 256);
  aggregate7<<<gG, 256, 0, stream>>>(FT8, el, er, rowptr, csrp, XA, nullptr, hfb, 1, N);
  // edge MLP (MFMA, CSR-ordered for dst-row locality)
  edge_mlp_csr<<<2048, 256, 0, stream>>>(hfb, csrp, Wm1c, bm1c, Wm2c, bm2c,
                                         d_out, E, flag);
}